// Round 9
// baseline (515.186 us; speedup 1.0000x reference)
//
#include <hip/hip_runtime.h>

#define NA    50000
#define NFEAT 512
#define HID   512
#define NC    128
#define AH    64
#define NE    800000
#define NHOP  4
#define NBUCK 196      // ceil(NA/256) buckets of 256 rows
#define CAPB  5120     // per-bucket capacity (mean 4082 -> 16 sigma headroom)

typedef __bf16 bf16x8 __attribute__((ext_vector_type(8)));
typedef float  f32x4  __attribute__((ext_vector_type(4)));

__device__ __forceinline__ unsigned short f2bf(float f){
  union { float f; unsigned u; } a; a.f = f;
  return (unsigned short)((a.u + 0x7fffu + ((a.u >> 16) & 1u)) >> 16);  // RNE
}
__device__ __forceinline__ float bf2f(unsigned short h){
  union { unsigned u; float f; } a; a.u = ((unsigned)h) << 16;
  return a.f;
}
__device__ __forceinline__ float uasf(unsigned u){
  union { unsigned u; float f; } a; a.u = u;
  return a.f;
}
__device__ __forceinline__ float tanh_fast(float x){
  x = fminf(15.f, fmaxf(-15.f, x));
  float e = __expf(2.f * x);
  return (e - 1.f) / (e + 1.f);
}

__device__ __forceinline__ void g2l16(const void* g, void* l){
  __builtin_amdgcn_global_load_lds(
      (const __attribute__((address_space(1))) void*)g,
      (__attribute__((address_space(3))) void*)l, 16, 0, 0);
}

// ---------------- casts / weight prep ----------------

__global__ void cast_x_kernel(const float* __restrict__ in, unsigned short* __restrict__ out, int n4){
  int i = blockIdx.x * 256 + threadIdx.x;
  if (i >= n4) return;
  float4 v = reinterpret_cast<const float4*>(in)[i];
  ushort4 o; o.x = f2bf(v.x); o.y = f2bf(v.y); o.z = f2bf(v.z); o.w = f2bf(v.w);
  reinterpret_cast<ushort4*>(out)[i] = o;
}

// in [R][N] f32 -> out [N][R] bf16 (i.e. out = in^T)
__global__ void transpose_cast_kernel(const float* __restrict__ in, unsigned short* __restrict__ out,
                                      int R, int N){
  int i = blockIdx.x * 256 + threadIdx.x;
  if (i >= R * N) return;
  int n = i / R, k = i - n * R;
  out[i] = f2bf(in[(size_t)k * N + n]);
}

// WaT [n=128][k=128] bf16: n<64 -> Wa[k][n] (top half), n>=64 -> Wa[128+k][n-64] (bottom half)
__global__ void build_wa_kernel(const float* __restrict__ Wa, unsigned short* __restrict__ WaT){
  int i = blockIdx.x * 256 + threadIdx.x;
  if (i >= 128 * 128) return;
  int n = i >> 7, k = i & 127;
  float v = (n < 64) ? Wa[(size_t)k * AH + n] : Wa[(size_t)(128 + k) * AH + (n - 64)];
  WaT[i] = f2bf(v);
}

// WfuseT[j][n] = sum_k Wa_bot[k][j] * Wg[n][k]   ([64][128] bf16; EWf = agg @ Wfuse)
__global__ void wfuse_kernel(const float* __restrict__ Wa, const float* __restrict__ Wg,
                             unsigned short* __restrict__ WfuseT){
  int i = blockIdx.x * 256 + threadIdx.x;
  if (i >= 64 * 128) return;
  int j = i >> 7, n = i & 127;
  float s = 0.f;
  for (int k = 0; k < 128; k++)
    s += Wa[(size_t)(128 + k) * AH + j] * Wg[(size_t)n * 128 + k];
  WfuseT[i] = f2bf(s);
}

// ---------------- bf16 MFMA GEMM:  C = A[M,K] x BT[N,K]^T ----------------
// OP: 0 relu->bf16   1 +bias -> f32 + bf16 + tile-major zt
// SWZ: XCD-affine dispatch (4 col-blocks of a row-block on one XCD)
template<int OP, int SWZ>
__global__ __launch_bounds__(256) void gemm_bt(
    const unsigned short* __restrict__ A, const unsigned short* __restrict__ BT,
    float* __restrict__ Cf, unsigned short* __restrict__ Cb,
    unsigned short* __restrict__ Czt,
    const float* __restrict__ bias,
    int M, int N, int K)
{
  int row0, col0;
  if (SWZ){
    const int xcd = blockIdx.x & 7, slot = blockIdx.x >> 3;
    const int r = xcd * 49 + (slot >> 2);
    if (r >= 391) return;
    row0 = r * 128; col0 = (slot & 3) * 128;
  } else {
    row0 = blockIdx.x * 128; col0 = blockIdx.y * 128;
  }
  __shared__ unsigned short As[128 * 32];
  __shared__ unsigned short Bs[128 * 32];
  const int tid = threadIdx.x;
  const int wave = tid >> 6, lane = tid & 63;
  const int wr = (wave >> 1) * 64, wc = (wave & 1) * 64;
  f32x4 acc[4][4];
  #pragma unroll
  for (int m = 0; m < 4; m++)
    #pragma unroll
    for (int n = 0; n < 4; n++) acc[m][n] = (f32x4){0.f, 0.f, 0.f, 0.f};
  const int lrow = lane >> 2, lk = (lane & 3) * 8;

  for (int k0 = 0; k0 < K; k0 += 32){
    __syncthreads();
    #pragma unroll
    for (int j = 0; j < 2; j++){
      const int rb = (wave * 2 + j) * 16;       // wave-uniform LDS base row
      const int ra = rb + lrow;
      int gr = row0 + ra; gr = gr < M ? gr : M - 1;
      g2l16(A + (size_t)gr * K + k0 + lk, As + rb * 32);
      int gc = col0 + ra; gc = gc < N ? gc : N - 1;
      g2l16(BT + (size_t)gc * K + k0 + lk, Bs + rb * 32);
    }
    __syncthreads();
    bf16x8 af[4], bfr[4];
    #pragma unroll
    for (int m = 0; m < 4; m++)
      af[m] = *reinterpret_cast<const bf16x8*>(&As[(wr + m * 16 + (lane & 15)) * 32 + (lane >> 4) * 8]);
    #pragma unroll
    for (int n = 0; n < 4; n++)
      bfr[n] = *reinterpret_cast<const bf16x8*>(&Bs[(wc + n * 16 + (lane & 15)) * 32 + (lane >> 4) * 8]);
    #pragma unroll
    for (int m = 0; m < 4; m++)
      #pragma unroll
      for (int n = 0; n < 4; n++)
        acc[m][n] = __builtin_amdgcn_mfma_f32_16x16x32_bf16(af[m], bfr[n], acc[m][n], 0, 0, 0);
  }

  const int rbase = row0 + wr + (lane >> 4) * 4;
  const int cbase = col0 + wc + (lane & 15);
  #pragma unroll
  for (int m = 0; m < 4; m++){
    #pragma unroll
    for (int n = 0; n < 4; n++){
      const int col = cbase + n * 16;
      #pragma unroll
      for (int i = 0; i < 4; i++){
        const int row = rbase + m * 16 + i;
        if (row < M && col < N){
          float v = acc[m][n][i];
          if (OP == 0){ v = v > 0.f ? v : 0.f; Cb[(size_t)row * N + col] = f2bf(v); }
          else {
            v += bias[col];
            Cf[(size_t)row * N + col] = v;
            unsigned short b = f2bf(v);
            Cb[(size_t)row * N + col] = b;
            Czt[((size_t)(col >> 5) * NA + row) * 32 + (col & 31)] = b;   // tile-major
          }
        }
      }
    }
  }
}

// ---------------- merged small-GEMM sweep (9 slices, K=128, M=NA) ----------------
// z 0-3: embs_h = agg_h @ Wg      (N=128, bf16 out)
// z 4-7: EWf_h  = agg_h @ Wfuse   (N=64,  bf16 out)  [EW = emb@Wa_bot == agg@(Wg@Wa_bot)]
// z 8  : ZW     = zbf @ [Wa_top|Wa_bot]  (N=128, f32 out)
__global__ __launch_bounds__(256) void gemm_sweep(
    const unsigned short* __restrict__ aggbf, const unsigned short* __restrict__ zbf,
    const unsigned short* __restrict__ WgT, const unsigned short* __restrict__ WfuseT,
    const unsigned short* __restrict__ WaT,
    unsigned short* __restrict__ embs, unsigned short* __restrict__ EW, float* __restrict__ ZW)
{
  const int zi = blockIdx.z;
  const unsigned short* A; const unsigned short* BT;
  unsigned short* Cb = nullptr; float* Cf = nullptr; int N;
  if (zi < 4)      { A = aggbf + (size_t)zi * NA * NC;       BT = WgT;    Cb = embs + (size_t)zi * NA * NC; N = 128; }
  else if (zi < 8) { A = aggbf + (size_t)(zi - 4) * NA * NC; BT = WfuseT; Cb = EW + (size_t)(zi - 4) * NA * AH; N = 64; }
  else             { A = zbf;                                BT = WaT;    Cf = ZW; N = 128; }

  __shared__ unsigned short As[128 * 32];
  __shared__ unsigned short Bs[128 * 32];
  const int tid = threadIdx.x;
  const int wave = tid >> 6, lane = tid & 63;
  const int row0 = blockIdx.x * 128;
  const int wr = (wave >> 1) * 64, wc = (wave & 1) * 64;
  f32x4 acc[4][4];
  #pragma unroll
  for (int m = 0; m < 4; m++)
    #pragma unroll
    for (int n = 0; n < 4; n++) acc[m][n] = (f32x4){0.f, 0.f, 0.f, 0.f};

  for (int k0 = 0; k0 < 128; k0 += 32){
    __syncthreads();
    #pragma unroll
    for (int j = 0; j < 2; j++){
      const int rb = (wave * 2 + j) * 16;
      int gr = row0 + rb + (lane >> 2); gr = gr < NA ? gr : NA - 1;
      g2l16(A + (size_t)gr * 128 + k0 + (lane & 3) * 8, As + rb * 32);
      int gc = rb + (lane >> 2); gc = gc < N ? gc : N - 1;
      g2l16(BT + (size_t)gc * 128 + k0 + (lane & 3) * 8, Bs + rb * 32);
    }
    __syncthreads();
    bf16x8 bfr[4];
    #pragma unroll
    for (int n = 0; n < 4; n++)
      bfr[n] = *reinterpret_cast<const bf16x8*>(&Bs[(wc + n * 16 + (lane & 15)) * 32 + (lane >> 4) * 8]);
    #pragma unroll
    for (int m = 0; m < 4; m++){
      bf16x8 a = *reinterpret_cast<const bf16x8*>(&As[(wr + m * 16 + (lane & 15)) * 32 + (lane >> 4) * 8]);
      #pragma unroll
      for (int n = 0; n < 4; n++)
        acc[m][n] = __builtin_amdgcn_mfma_f32_16x16x32_bf16(a, bfr[n], acc[m][n], 0, 0, 0);
    }
  }

  const int rbase = row0 + wr + (lane >> 4) * 4;
  const int cbase = wc + (lane & 15);
  #pragma unroll
  for (int m = 0; m < 4; m++){
    #pragma unroll
    for (int n = 0; n < 4; n++){
      const int col = cbase + n * 16;
      #pragma unroll
      for (int i = 0; i < 4; i++){
        const int row = rbase + m * 16 + i;
        if (row < NA && col < N){
          float v = acc[m][n][i];
          if (Cf) Cf[(size_t)row * N + col] = v;
          else    Cb[(size_t)row * N + col] = f2bf(v);
        }
      }
    }
  }
}

// ---------------- two-level binned CSR build ----------------
// Record: lo32 = val bits, hi32 = (localrow<<17)|col
__global__ __launch_bounds__(256) void binA_kernel(
    const int* __restrict__ adji, const float* __restrict__ adjv,
    int* __restrict__ fill, long long* __restrict__ binned)
{
  const int h = blockIdx.y, tid = threadIdx.x;
  const int e0 = blockIdx.x * 2048;
  __shared__ int lhist[NBUCK], lbase[NBUCK], lfill[NBUCK];
  for (int i = tid; i < NBUCK; i += 256){ lhist[i] = 0; lfill[i] = 0; }
  __syncthreads();
  int rr[8]; unsigned hh[8]; float vv[8];
  #pragma unroll
  for (int k = 0; k < 8; k++){
    int e = e0 + k * 256 + tid;
    bool ok = e < NE;
    int r = ok ? adji[(size_t)h * 2 * NE + e] : -1;
    int c = ok ? adji[(size_t)h * 2 * NE + NE + e] : 0;
    vv[k] = ok ? adjv[(size_t)h * NE + e] : 0.f;
    rr[k] = r;
    hh[k] = ((unsigned)(r & 255) << 17) | (unsigned)c;
    if (ok) atomicAdd(&lhist[r >> 8], 1);
  }
  __syncthreads();
  if (tid < NBUCK) lbase[tid] = atomicAdd(&fill[h * NBUCK + tid], lhist[tid]);
  __syncthreads();
  #pragma unroll
  for (int k = 0; k < 8; k++){
    if (rr[k] >= 0){
      int b = rr[k] >> 8;
      int p = lbase[b] + atomicAdd(&lfill[b], 1);
      if (p < CAPB)
        binned[((size_t)(h * NBUCK + b)) * CAPB + p] =
            ((long long)hh[k] << 32) | (unsigned)__float_as_int(vv[k]);
    }
  }
}

__global__ __launch_bounds__(1024) void bscan_kernel(const int* __restrict__ fill,
                                                     int* __restrict__ bbase, int* __restrict__ offs){
  __shared__ int tmp[1024];
  int tid = threadIdx.x;
  int v = (tid < NHOP * NBUCK) ? fill[tid] : 0;
  tmp[tid] = v; __syncthreads();
  for (int o = 1; o < 1024; o <<= 1){
    int t = (tid >= o) ? tmp[tid - o] : 0;
    __syncthreads();
    tmp[tid] += t;
    __syncthreads();
  }
  if (tid < NHOP * NBUCK) bbase[tid] = tmp[tid] - v;
  if (tid == 0) offs[NHOP * NA] = NHOP * NE;
}

__global__ __launch_bounds__(256) void binB_kernel(
    const int* __restrict__ fill, const int* __restrict__ bbase,
    const long long* __restrict__ binned,
    int* __restrict__ offs, long long* __restrict__ pvc)
{
  const int b = blockIdx.x, h = blockIdx.y, tid = threadIdx.x;
  const int hb = h * NBUCK + b;
  const int cnt = min(fill[hb], CAPB);
  const long long* src = binned + (size_t)hb * CAPB;
  const int gbase = bbase[hb];
  const int rowbase = b << 8;
  const int nrows = min(256, NA - rowbase);
  __shared__ long long sdata[CAPB];
  __shared__ int lhist[256], lpre[256], lfill2[256];
  lhist[tid] = 0; lfill2[tid] = 0;
  __syncthreads();
  for (int p = tid; p < cnt; p += 256)
    atomicAdd(&lhist[(unsigned)(src[p] >> 32) >> 17], 1);
  __syncthreads();
  int v = lhist[tid]; lpre[tid] = v; __syncthreads();
  for (int o = 1; o < 256; o <<= 1){
    int t = (tid >= o) ? lpre[tid - o] : 0;
    __syncthreads();
    lpre[tid] += t;
    __syncthreads();
  }
  int excl = lpre[tid] - v;
  if (tid < nrows) offs[h * NA + rowbase + tid] = gbase + excl;
  lpre[tid] = excl;
  __syncthreads();
  for (int p = tid; p < cnt; p += 256){
    long long rec = src[p];
    unsigned hi = (unsigned)(rec >> 32);
    int lr = hi >> 17;
    long long out = (rec & 0xffffffffLL) | ((long long)(hi & 0x1ffffu) << 32);
    int pos = lpre[lr] + atomicAdd(&lfill2[lr], 1);
    if (pos < CAPB) sdata[pos] = out;
    else            pvc[(size_t)gbase + pos] = out;
  }
  __syncthreads();
  for (int p = tid; p < cnt; p += 256)
    pvc[(size_t)gbase + p] = sdata[p];
}

// ---------------- channel-tiled XCD-affine gather v3 ----------------
// agg[h][r][c] = sum_e v_e * z[col_e][c], per 32-ch tile on tile-major zt.
// tile = (blockIdx.x&7)>>1, grid.x = 50000 = 0 mod 8 -> each XCD pins one
// 3.2MB zt slice in its L2 (2 XCDs/tile). Wave = one row; its four 16-lane
// groups each process ONE edge across 16 z-dwords (64B coalesced, L2-hit).
// Records staged to LDS (same-wave, no barrier), re-read as 4-address
// ds_read_b64 broadcast. Cross-group combine: shfl_xor 16/32. Padding recs
// are 0 -> v=0, reads zt row 0, contributes 0.
#define GR 4
__global__ __launch_bounds__(256) void gather_kernel(
    const int* __restrict__ offs, const long long* __restrict__ pvc,
    const unsigned short* __restrict__ zt, unsigned short* __restrict__ aggbf)
{
  const int t  = (blockIdx.x & 7) >> 1;
  const int rc = (blockIdx.x >> 3) * 2 + (blockIdx.x & 1);
  const int h = blockIdx.y;
  const int w = threadIdx.x >> 6, lane = threadIdx.x & 63;
  const int g = lane >> 4, cl = lane & 15;     // edge-group, channel-dword
  const int row = rc * GR + w;
  const int base = h * NA + row;
  const int s = offs[base], e = offs[base + 1];
  __shared__ alignas(16) long long srec[GR][64];
  const unsigned* zt32 = (const unsigned*)(zt + (size_t)t * NA * 32);
  const long long* sr = &srec[w][0];
  float a0 = 0.f, a1 = 0.f;
  for (int p0 = s; p0 < e; p0 += 64){
    long long r = 0;
    if (p0 + lane < e) r = __builtin_nontemporal_load(&pvc[p0 + lane]);
    srec[w][lane] = r;                          // same-wave RAW: lgkmcnt, no barrier
    const int quads = (min(64, e - p0) + 3) >> 2;
    #pragma unroll 4
    for (int q = 0; q < quads; q++){
      long long rec = sr[q * 4 + g];            // 4 addrs, broadcast within group
      float    v = uasf((unsigned)rec);
      unsigned c = (unsigned)(rec >> 32);
      unsigned zd = zt32[(c << 4) + cl];        // 64B per 16-lane group, L2-hit
      a0 += v * uasf(zd << 16);
      a1 += v * uasf(zd & 0xffff0000u);
    }
  }
  a0 += __shfl_xor(a0, 16); a0 += __shfl_xor(a0, 32);
  a1 += __shfl_xor(a1, 16); a1 += __shfl_xor(a1, 32);
  if (g == 0){
    ushort2 o; o.x = f2bf(a0); o.y = f2bf(a1);
    *reinterpret_cast<ushort2*>(aggbf + (size_t)base * NC + t * 32 + cl * 2) = o;
  }
}

// ---------------- fused attention epilogue ----------------
__global__ __launch_bounds__(256) void final_kernel(
    const float* __restrict__ z, const unsigned short* __restrict__ embs,
    const float* __restrict__ ZW, const unsigned short* __restrict__ EW,
    const float* __restrict__ ba, const float* __restrict__ va,
    const int* __restrict__ idx, float* __restrict__ out)
{
  int tid = threadIdx.x, wave = tid >> 6, lane = tid & 63;
  int n = blockIdx.x * 4 + wave;
  if (n >= NA) return;
  int an = idx[n];
  float qa = ZW[(size_t)an * NC + lane] + ba[lane];
  float vaj = va[lane];
  float sc[5];
  {
    float s0 = ZW[(size_t)an * NC + 64 + lane];
    float t = tanh_fast(qa + s0) * vaj;
    #pragma unroll
    for (int o = 32; o; o >>= 1) t += __shfl_xor(t, o);
    sc[0] = t;
  }
  #pragma unroll
  for (int h = 1; h < 5; h++){
    float sh = bf2f(EW[((size_t)(h - 1) * NA + n) * AH + lane]);
    float t = tanh_fast(qa + sh) * vaj;
    #pragma unroll
    for (int o = 32; o; o >>= 1) t += __shfl_xor(t, o);
    sc[h] = t;
  }
  float m = sc[0];
  #pragma unroll
  for (int h = 1; h < 5; h++) m = fmaxf(m, sc[h]);
  float al[5], den = 0.f;
  #pragma unroll
  for (int h = 0; h < 5; h++){ al[h] = __expf(sc[h] - m); den += al[h]; }
  float inv = 1.f / den;
  float o0 = al[0] * z[(size_t)an * NC + lane];
  float o1 = al[0] * z[(size_t)an * NC + 64 + lane];
  #pragma unroll
  for (int h = 1; h < 5; h++){
    o0 += al[h] * bf2f(embs[((size_t)(h - 1) * NA + n) * NC + lane]);
    o1 += al[h] * bf2f(embs[((size_t)(h - 1) * NA + n) * NC + 64 + lane]);
  }
  o0 *= inv; o1 *= inv;
  float mx = fmaxf(o0, o1);
  #pragma unroll
  for (int o = 32; o; o >>= 1) mx = fmaxf(mx, __shfl_xor(mx, o));
  float se = __expf(o0 - mx) + __expf(o1 - mx);
  #pragma unroll
  for (int o = 32; o; o >>= 1) se += __shfl_xor(se, o);
  float ls = __logf(se);
  out[(size_t)n * NC + lane]      = o0 - mx - ls;
  out[(size_t)n * NC + 64 + lane] = o1 - mx - ls;
}

// ---------------- launch ----------------

extern "C" void kernel_launch(void* const* d_in, const int* in_sizes, int n_in,
                              void* d_out, int out_size, void* d_ws, size_t ws_size,
                              hipStream_t stream)
{
  const float* x    = (const float*)d_in[0];
  const float* W1   = (const float*)d_in[1];
  const float* W2   = (const float*)d_in[2];
  const float* b2   = (const float*)d_in[3];
  const float* Wg   = (const float*)d_in[4];
  const float* Wa   = (const float*)d_in[5];
  const float* ba   = (const float*)d_in[6];
  const float* va   = (const float*)d_in[7];
  const float* adjv = (const float*)d_in[8];
  const int*   adji = (const int*)d_in[9];
  const int*   idx  = (const int*)d_in[10];
  float* out = (float*)d_out;
  (void)in_sizes; (void)n_in; (void)out_size; (void)ws_size;

  char* w = (char*)d_ws;
  auto alloc = [&](size_t b) -> char* { char* p = w; w += (b + 255) & ~(size_t)255; return p; };
  unsigned short* Scr1 = (unsigned short*)alloc((size_t)NA * NFEAT * 2);  // 51.2MB: Xbf -> binned -> embs
  unsigned short* Hbuf = (unsigned short*)alloc((size_t)NA * HID * 2);    // 51.2MB: GEMM1 out -> aggbf
  unsigned short* W1T  = (unsigned short*)alloc((size_t)HID * NFEAT * 2);
  unsigned short* W2T  = (unsigned short*)alloc((size_t)NC * HID * 2);
  unsigned short* WgT  = (unsigned short*)alloc((size_t)NC * NC * 2);
  unsigned short* WaT  = (unsigned short*)alloc((size_t)NC * NC * 2);
  unsigned short* WfuseT = (unsigned short*)alloc((size_t)AH * NC * 2);
  float*          z    = (float*)alloc((size_t)NA * NC * 4);
  unsigned short* zbf  = (unsigned short*)alloc((size_t)NA * NC * 2);
  unsigned short* zt   = (unsigned short*)alloc((size_t)NA * NC * 2);     // tile-major [4][NA][32]
  float*          ZW   = (float*)alloc((size_t)NA * NC * 4);
  int* fill  = (int*)alloc((size_t)NHOP * NBUCK * 4);
  int* bbase = (int*)alloc((size_t)NHOP * NBUCK * 4);
  int* offs  = (int*)alloc(((size_t)NHOP * NA + 1) * 4);
  long long* pvc = (long long*)alloc((size_t)NHOP * NE * 8);              // CSR records {val,col}
  unsigned short* Xbf   = Scr1;                  // x bf16 (consumed by GEMM1)
  long long* binned     = (long long*)Scr1;      // live binA..binB (after GEMM1)
  unsigned short* embs  = Scr1;                  // [4][NA][NC] bf16 (after binB)
  unsigned short* aggbf = Hbuf;                  // [4][NA][NC] bf16 (after GEMM2)
  unsigned short* EW    = (unsigned short*)pvc;  // [4][NA][64] bf16 (pvc dead after gather)

  // casts / weight prep
  cast_x_kernel<<<dim3((NA * NFEAT / 4 + 255) / 256), 256, 0, stream>>>(x, Xbf, NA * NFEAT / 4);
  transpose_cast_kernel<<<dim3((NFEAT * HID + 255) / 256), 256, 0, stream>>>(W1, W1T, NFEAT, HID);
  transpose_cast_kernel<<<dim3((HID * NC + 255) / 256), 256, 0, stream>>>(W2, W2T, HID, NC);
  transpose_cast_kernel<<<dim3((NC * NC + 255) / 256), 256, 0, stream>>>(Wg, WgT, NC, NC);
  build_wa_kernel<<<dim3(64), 256, 0, stream>>>(Wa, WaT);
  wfuse_kernel<<<dim3(32), 256, 0, stream>>>(Wa, Wg, WfuseT);

  // z = relu(x@W1)@W2 + b2   (GEMM1 XCD-affine; GEMM2 also writes tile-major zt)
  gemm_bt<0, 1><<<dim3(1568, 1, 1), 256, 0, stream>>>(Xbf, W1T, nullptr, Hbuf, nullptr, nullptr, NA, HID, NFEAT);
  gemm_bt<1, 0><<<dim3(391, 1, 1), 256, 0, stream>>>(Hbuf, W2T, z, zbf, zt, b2, NA, NC, HID);

  // CSR build: bin -> scan -> fine sort (Xbf dead now; binned aliases it)
  hipMemsetAsync(fill, 0, (size_t)NHOP * NBUCK * 4, stream);
  binA_kernel<<<dim3((NE + 2047) / 2048, NHOP), 256, 0, stream>>>(adji, adjv, fill, binned);
  bscan_kernel<<<dim3(1), 1024, 0, stream>>>(fill, bbase, offs);
  binB_kernel<<<dim3(NBUCK, NHOP), 256, 0, stream>>>(fill, bbase, binned, offs, pvc);

  // aggregate (channel-tiled v3), then one merged 9-slice GEMM launch
  gather_kernel<<<dim3(50000, NHOP), 256, 0, stream>>>(offs, pvc, zt, aggbf);
  gemm_sweep<<<dim3(391, 1, 9), 256, 0, stream>>>(aggbf, zbf, WgT, WfuseT, WaT, embs, EW, ZW);

  // fused softmax-attention + log_softmax
  final_kernel<<<dim3(NA / 4), 256, 0, stream>>>(z, embs, ZW, EW, ba, va, idx, out);
}

// Round 10
// 341.176 us; speedup vs baseline: 1.5100x; 1.5100x over previous
//
#include <hip/hip_runtime.h>

#define NA    50000
#define NFEAT 512
#define HID   512
#define NC    128
#define AH    64
#define NE    800000
#define NHOP  4
#define NBUCK 196      // ceil(NA/256) buckets of 256 rows
#define CAPB  5120     // per-bucket capacity (mean 4082 -> 16 sigma headroom)

typedef __bf16 bf16x8 __attribute__((ext_vector_type(8)));
typedef float  f32x4  __attribute__((ext_vector_type(4)));

__device__ __forceinline__ unsigned short f2bf(float f){
  union { float f; unsigned u; } a; a.f = f;
  return (unsigned short)((a.u + 0x7fffu + ((a.u >> 16) & 1u)) >> 16);  // RNE
}
__device__ __forceinline__ float bf2f(unsigned short h){
  union { unsigned u; float f; } a; a.u = ((unsigned)h) << 16;
  return a.f;
}
__device__ __forceinline__ float uasf(unsigned u){
  union { unsigned u; float f; } a; a.u = u;
  return a.f;
}
__device__ __forceinline__ float tanh_fast(float x){
  x = fminf(15.f, fmaxf(-15.f, x));
  float e = __expf(2.f * x);
  return (e - 1.f) / (e + 1.f);
}

__device__ __forceinline__ void g2l16(const void* g, void* l){
  __builtin_amdgcn_global_load_lds(
      (const __attribute__((address_space(1))) void*)g,
      (__attribute__((address_space(3))) void*)l, 16, 0, 0);
}

// ---------------- x cast ----------------

__global__ void cast_x_kernel(const float* __restrict__ in, unsigned short* __restrict__ out, int n4){
  int i = blockIdx.x * 256 + threadIdx.x;
  if (i >= n4) return;
  float4 v = reinterpret_cast<const float4*>(in)[i];
  ushort4 o; o.x = f2bf(v.x); o.y = f2bf(v.y); o.z = f2bf(v.z); o.w = f2bf(v.w);
  reinterpret_cast<ushort4*>(out)[i] = o;
}

// ---------------- merged weight prep (one launch) ----------------
// b<1024: W1T    [512][512] = W1^T
// b<1280: W2T    [128][512] = W2^T
// b<1344: WgT    [128][128] = Wg^T
// b<1408: WaT    [128][128] = [Wa_top | Wa_bot] packed (n<64 top, n>=64 bottom)
// b<1440: WfuseT [64][128]  : Wfuse[j][n] = sum_k Wa_bot[k][j]*Wg[n][k]
__global__ void prep_kernel(const float* __restrict__ W1, const float* __restrict__ W2,
                            const float* __restrict__ Wg, const float* __restrict__ Wa,
                            unsigned short* __restrict__ W1T, unsigned short* __restrict__ W2T,
                            unsigned short* __restrict__ WgT, unsigned short* __restrict__ WaT,
                            unsigned short* __restrict__ WfuseT){
  const int b = blockIdx.x, tid = threadIdx.x;
  if (b < 1024){
    int i = b * 256 + tid;                       // 262144
    int n = i >> 9, k = i & 511;
    W1T[i] = f2bf(W1[(size_t)k * HID + n]);
  } else if (b < 1280){
    int i = (b - 1024) * 256 + tid;              // 65536
    int n = i >> 9, k = i & 511;
    W2T[i] = f2bf(W2[(size_t)k * NC + n]);
  } else if (b < 1344){
    int i = (b - 1280) * 256 + tid;              // 16384
    int n = i >> 7, k = i & 127;
    WgT[i] = f2bf(Wg[(size_t)k * NC + n]);
  } else if (b < 1408){
    int i = (b - 1344) * 256 + tid;              // 16384
    int n = i >> 7, k = i & 127;
    float v = (n < 64) ? Wa[(size_t)k * AH + n] : Wa[(size_t)(128 + k) * AH + (n - 64)];
    WaT[i] = f2bf(v);
  } else {
    int i = (b - 1408) * 256 + tid;              // 8192
    int j = i >> 7, n = i & 127;
    float s = 0.f;
    for (int k = 0; k < 128; k++)
      s += Wa[(size_t)(128 + k) * AH + j] * Wg[(size_t)n * 128 + k];
    WfuseT[i] = f2bf(s);
  }
}

// ---------------- bf16 MFMA GEMM:  C = A[M,K] x BT[N,K]^T ----------------
// OP: 0 relu->bf16   1 +bias->bf16
// SWZ: XCD-affine dispatch (4 col-blocks of a row-block on one XCD)
template<int OP, int SWZ>
__global__ __launch_bounds__(256) void gemm_bt(
    const unsigned short* __restrict__ A, const unsigned short* __restrict__ BT,
    unsigned short* __restrict__ Cb, const float* __restrict__ bias,
    int M, int N, int K)
{
  int row0, col0;
  if (SWZ){
    const int xcd = blockIdx.x & 7, slot = blockIdx.x >> 3;
    const int r = xcd * 49 + (slot >> 2);
    if (r >= 391) return;
    row0 = r * 128; col0 = (slot & 3) * 128;
  } else {
    row0 = blockIdx.x * 128; col0 = blockIdx.y * 128;
  }
  __shared__ unsigned short As[128 * 32];
  __shared__ unsigned short Bs[128 * 32];
  const int tid = threadIdx.x;
  const int wave = tid >> 6, lane = tid & 63;
  const int wr = (wave >> 1) * 64, wc = (wave & 1) * 64;
  f32x4 acc[4][4];
  #pragma unroll
  for (int m = 0; m < 4; m++)
    #pragma unroll
    for (int n = 0; n < 4; n++) acc[m][n] = (f32x4){0.f, 0.f, 0.f, 0.f};
  const int lrow = lane >> 2, lk = (lane & 3) * 8;

  for (int k0 = 0; k0 < K; k0 += 32){
    __syncthreads();
    #pragma unroll
    for (int j = 0; j < 2; j++){
      const int rb = (wave * 2 + j) * 16;       // wave-uniform LDS base row
      const int ra = rb + lrow;
      int gr = row0 + ra; gr = gr < M ? gr : M - 1;
      g2l16(A + (size_t)gr * K + k0 + lk, As + rb * 32);
      int gc = col0 + ra; gc = gc < N ? gc : N - 1;
      g2l16(BT + (size_t)gc * K + k0 + lk, Bs + rb * 32);
    }
    __syncthreads();
    bf16x8 af[4], bfr[4];
    #pragma unroll
    for (int m = 0; m < 4; m++)
      af[m] = *reinterpret_cast<const bf16x8*>(&As[(wr + m * 16 + (lane & 15)) * 32 + (lane >> 4) * 8]);
    #pragma unroll
    for (int n = 0; n < 4; n++)
      bfr[n] = *reinterpret_cast<const bf16x8*>(&Bs[(wc + n * 16 + (lane & 15)) * 32 + (lane >> 4) * 8]);
    #pragma unroll
    for (int m = 0; m < 4; m++)
      #pragma unroll
      for (int n = 0; n < 4; n++)
        acc[m][n] = __builtin_amdgcn_mfma_f32_16x16x32_bf16(af[m], bfr[n], acc[m][n], 0, 0, 0);
  }

  const int rbase = row0 + wr + (lane >> 4) * 4;
  const int cbase = col0 + wc + (lane & 15);
  #pragma unroll
  for (int m = 0; m < 4; m++){
    #pragma unroll
    for (int n = 0; n < 4; n++){
      const int col = cbase + n * 16;
      #pragma unroll
      for (int i = 0; i < 4; i++){
        const int row = rbase + m * 16 + i;
        if (row < M && col < N){
          float v = acc[m][n][i];
          if (OP == 0){ v = v > 0.f ? v : 0.f; }
          else        { v += bias[col]; }
          Cb[(size_t)row * N + col] = f2bf(v);
        }
      }
    }
  }
}

// ---------------- merged small-GEMM sweep (9 slices, K=128, M=NA) ----------------
// z 0-3: embs_h = agg_h @ Wg      (N=128, bf16 out)
// z 4-7: EWf_h  = agg_h @ Wfuse   (N=64,  bf16 out)  [EW = emb@Wa_bot == agg@(Wg@Wa_bot)]
// z 8  : ZW     = zbf @ [Wa_top|Wa_bot]  (N=128, f32 out)
__global__ __launch_bounds__(256) void gemm_sweep(
    const unsigned short* __restrict__ aggbf, const unsigned short* __restrict__ zbf,
    const unsigned short* __restrict__ WgT, const unsigned short* __restrict__ WfuseT,
    const unsigned short* __restrict__ WaT,
    unsigned short* __restrict__ embs, unsigned short* __restrict__ EW, float* __restrict__ ZW)
{
  const int zi = blockIdx.z;
  const unsigned short* A; const unsigned short* BT;
  unsigned short* Cb = nullptr; float* Cf = nullptr; int N;
  if (zi < 4)      { A = aggbf + (size_t)zi * NA * NC;       BT = WgT;    Cb = embs + (size_t)zi * NA * NC; N = 128; }
  else if (zi < 8) { A = aggbf + (size_t)(zi - 4) * NA * NC; BT = WfuseT; Cb = EW + (size_t)(zi - 4) * NA * AH; N = 64; }
  else             { A = zbf;                                BT = WaT;    Cf = ZW; N = 128; }

  __shared__ unsigned short As[128 * 32];
  __shared__ unsigned short Bs[128 * 32];
  const int tid = threadIdx.x;
  const int wave = tid >> 6, lane = tid & 63;
  const int row0 = blockIdx.x * 128;
  const int wr = (wave >> 1) * 64, wc = (wave & 1) * 64;
  f32x4 acc[4][4];
  #pragma unroll
  for (int m = 0; m < 4; m++)
    #pragma unroll
    for (int n = 0; n < 4; n++) acc[m][n] = (f32x4){0.f, 0.f, 0.f, 0.f};

  for (int k0 = 0; k0 < 128; k0 += 32){
    __syncthreads();
    #pragma unroll
    for (int j = 0; j < 2; j++){
      const int rb = (wave * 2 + j) * 16;
      int gr = row0 + rb + (lane >> 2); gr = gr < NA ? gr : NA - 1;
      g2l16(A + (size_t)gr * 128 + k0 + (lane & 3) * 8, As + rb * 32);
      int gc = rb + (lane >> 2); gc = gc < N ? gc : N - 1;
      g2l16(BT + (size_t)gc * 128 + k0 + (lane & 3) * 8, Bs + rb * 32);
    }
    __syncthreads();
    bf16x8 bfr[4];
    #pragma unroll
    for (int n = 0; n < 4; n++)
      bfr[n] = *reinterpret_cast<const bf16x8*>(&Bs[(wc + n * 16 + (lane & 15)) * 32 + (lane >> 4) * 8]);
    #pragma unroll
    for (int m = 0; m < 4; m++){
      bf16x8 a = *reinterpret_cast<const bf16x8*>(&As[(wr + m * 16 + (lane & 15)) * 32 + (lane >> 4) * 8]);
      #pragma unroll
      for (int n = 0; n < 4; n++)
        acc[m][n] = __builtin_amdgcn_mfma_f32_16x16x32_bf16(a, bfr[n], acc[m][n], 0, 0, 0);
    }
  }

  const int rbase = row0 + wr + (lane >> 4) * 4;
  const int cbase = wc + (lane & 15);
  #pragma unroll
  for (int m = 0; m < 4; m++){
    #pragma unroll
    for (int n = 0; n < 4; n++){
      const int col = cbase + n * 16;
      #pragma unroll
      for (int i = 0; i < 4; i++){
        const int row = rbase + m * 16 + i;
        if (row < NA && col < N){
          float v = acc[m][n][i];
          if (Cf) Cf[(size_t)row * N + col] = v;
          else    Cb[(size_t)row * N + col] = f2bf(v);
        }
      }
    }
  }
}

// ---------------- two-level binned CSR build ----------------
// Record: lo32 = val bits, hi32 = (localrow<<17)|col
__global__ __launch_bounds__(256) void binA_kernel(
    const int* __restrict__ adji, const float* __restrict__ adjv,
    int* __restrict__ fill, long long* __restrict__ binned)
{
  const int h = blockIdx.y, tid = threadIdx.x;
  const int e0 = blockIdx.x * 2048;
  __shared__ int lhist[NBUCK], lbase[NBUCK], lfill[NBUCK];
  for (int i = tid; i < NBUCK; i += 256){ lhist[i] = 0; lfill[i] = 0; }
  __syncthreads();
  int rr[8]; unsigned hh[8]; float vv[8];
  #pragma unroll
  for (int k = 0; k < 8; k++){
    int e = e0 + k * 256 + tid;
    bool ok = e < NE;
    int r = ok ? adji[(size_t)h * 2 * NE + e] : -1;
    int c = ok ? adji[(size_t)h * 2 * NE + NE + e] : 0;
    vv[k] = ok ? adjv[(size_t)h * NE + e] : 0.f;
    rr[k] = r;
    hh[k] = ((unsigned)(r & 255) << 17) | (unsigned)c;
    if (ok) atomicAdd(&lhist[r >> 8], 1);
  }
  __syncthreads();
  if (tid < NBUCK) lbase[tid] = atomicAdd(&fill[h * NBUCK + tid], lhist[tid]);
  __syncthreads();
  #pragma unroll
  for (int k = 0; k < 8; k++){
    if (rr[k] >= 0){
      int b = rr[k] >> 8;
      int p = lbase[b] + atomicAdd(&lfill[b], 1);
      if (p < CAPB)
        binned[((size_t)(h * NBUCK + b)) * CAPB + p] =
            ((long long)hh[k] << 32) | (unsigned)__float_as_int(vv[k]);
    }
  }
}

__global__ __launch_bounds__(1024) void bscan_kernel(const int* __restrict__ fill,
                                                     int* __restrict__ bbase, int* __restrict__ offs){
  __shared__ int tmp[1024];
  int tid = threadIdx.x;
  int v = (tid < NHOP * NBUCK) ? fill[tid] : 0;
  tmp[tid] = v; __syncthreads();
  for (int o = 1; o < 1024; o <<= 1){
    int t = (tid >= o) ? tmp[tid - o] : 0;
    __syncthreads();
    tmp[tid] += t;
    __syncthreads();
  }
  if (tid < NHOP * NBUCK) bbase[tid] = tmp[tid] - v;
  if (tid == 0) offs[NHOP * NA] = NHOP * NE;
}

__global__ __launch_bounds__(256) void binB_kernel(
    const int* __restrict__ fill, const int* __restrict__ bbase,
    const long long* __restrict__ binned,
    int* __restrict__ offs, long long* __restrict__ pvc)
{
  const int b = blockIdx.x, h = blockIdx.y, tid = threadIdx.x;
  const int hb = h * NBUCK + b;
  const int cnt = min(fill[hb], CAPB);
  const long long* src = binned + (size_t)hb * CAPB;
  const int gbase = bbase[hb];
  const int rowbase = b << 8;
  const int nrows = min(256, NA - rowbase);
  __shared__ long long sdata[CAPB];
  __shared__ int lhist[256], lpre[256], lfill2[256];
  lhist[tid] = 0; lfill2[tid] = 0;
  __syncthreads();
  for (int p = tid; p < cnt; p += 256)
    atomicAdd(&lhist[(unsigned)(src[p] >> 32) >> 17], 1);
  __syncthreads();
  int v = lhist[tid]; lpre[tid] = v; __syncthreads();
  for (int o = 1; o < 256; o <<= 1){
    int t = (tid >= o) ? lpre[tid - o] : 0;
    __syncthreads();
    lpre[tid] += t;
    __syncthreads();
  }
  int excl = lpre[tid] - v;
  if (tid < nrows) offs[h * NA + rowbase + tid] = gbase + excl;
  lpre[tid] = excl;
  __syncthreads();
  for (int p = tid; p < cnt; p += 256){
    long long rec = src[p];
    unsigned hi = (unsigned)(rec >> 32);
    int lr = hi >> 17;
    long long out = (rec & 0xffffffffLL) | ((long long)(hi & 0x1ffffu) << 32);
    int pos = lpre[lr] + atomicAdd(&lfill2[lr], 1);
    if (pos < CAPB) sdata[pos] = out;
    else            pvc[(size_t)gbase + pos] = out;
  }
  __syncthreads();
  for (int p = tid; p < cnt; p += 256)
    pvc[(size_t)gbase + p] = sdata[p];
}

// ---------------- single-pass 128-channel gather, wave-per-row (r8 winner) ----------------
// One wave per row; lane owns channel pair -> one dword z-load per lane per
// edge (256B/wave, full-width). Records staged to LDS by coalesced wave load
// (same-wave only, no barrier), consumed wave-uniform as int4 (2 records) x2
// per iter -> 4 independent z loads; unroll 4 -> 16 in flight. Empirically
// optimal vs all channel-tiled variants (r2/r4/r9 all latency-bound).
#define GR 4
__global__ __launch_bounds__(256) void gather_kernel(
    const int* __restrict__ offs, const long long* __restrict__ pvc,
    const unsigned short* __restrict__ zbf, unsigned short* __restrict__ aggbf)
{
  const int h = blockIdx.y;
  const int w = threadIdx.x >> 6, lane = threadIdx.x & 63;
  const int row = blockIdx.x * GR + w;
  const int base = h * NA + row;
  const int s = offs[base], e = offs[base + 1];
  __shared__ alignas(16) long long srec[GR][64];
  const unsigned* z32 = (const unsigned*)zbf;   // [NA][64] dwords (2 bf16 each)
  const int4* sr2 = (const int4*)&srec[w][0];
  float a0 = 0.f, a1 = 0.f, b0 = 0.f, b1 = 0.f;
  for (int p0 = s; p0 < e; p0 += 64){
    long long r = 0;
    if (p0 + lane < e) r = __builtin_nontemporal_load(&pvc[p0 + lane]);
    srec[w][lane] = r;                          // all 64 lanes write -> padding stays 0
    const int quads = (min(64, e - p0) + 3) >> 2;
    #pragma unroll 4
    for (int q = 0; q < quads; q++){
      int4 ra = sr2[2 * q], rb = sr2[2 * q + 1];  // 4 records, wave-uniform broadcast
      unsigned z0 = z32[((unsigned)ra.y << 6) + lane];
      unsigned z1 = z32[((unsigned)ra.w << 6) + lane];
      unsigned z2 = z32[((unsigned)rb.y << 6) + lane];
      unsigned z3 = z32[((unsigned)rb.w << 6) + lane];
      float v0 = uasf((unsigned)ra.x), v1 = uasf((unsigned)ra.z);
      float v2 = uasf((unsigned)rb.x), v3 = uasf((unsigned)rb.z);
      a0 += v0 * uasf(z0 << 16); a1 += v0 * uasf(z0 & 0xffff0000u);
      b0 += v1 * uasf(z1 << 16); b1 += v1 * uasf(z1 & 0xffff0000u);
      a0 += v2 * uasf(z2 << 16); a1 += v2 * uasf(z2 & 0xffff0000u);
      b0 += v3 * uasf(z3 << 16); b1 += v3 * uasf(z3 & 0xffff0000u);
    }
  }
  ushort2 o; o.x = f2bf(a0 + b0); o.y = f2bf(a1 + b1);
  *reinterpret_cast<ushort2*>(aggbf + (size_t)base * NC + lane * 2) = o;
}

// ---------------- fused attention epilogue (bf16 anchor) ----------------
__global__ __launch_bounds__(256) void final_kernel(
    const unsigned short* __restrict__ zbf, const unsigned short* __restrict__ embs,
    const float* __restrict__ ZW, const unsigned short* __restrict__ EW,
    const float* __restrict__ ba, const float* __restrict__ va,
    const int* __restrict__ idx, float* __restrict__ out)
{
  int tid = threadIdx.x, wave = tid >> 6, lane = tid & 63;
  int n = blockIdx.x * 4 + wave;
  if (n >= NA) return;
  int an = idx[n];
  float qa = ZW[(size_t)an * NC + lane] + ba[lane];
  float vaj = va[lane];
  float sc[5];
  {
    float s0 = ZW[(size_t)an * NC + 64 + lane];
    float t = tanh_fast(qa + s0) * vaj;
    #pragma unroll
    for (int o = 32; o; o >>= 1) t += __shfl_xor(t, o);
    sc[0] = t;
  }
  #pragma unroll
  for (int h = 1; h < 5; h++){
    float sh = bf2f(EW[((size_t)(h - 1) * NA + n) * AH + lane]);
    float t = tanh_fast(qa + sh) * vaj;
    #pragma unroll
    for (int o = 32; o; o >>= 1) t += __shfl_xor(t, o);
    sc[h] = t;
  }
  float m = sc[0];
  #pragma unroll
  for (int h = 1; h < 5; h++) m = fmaxf(m, sc[h]);
  float al[5], den = 0.f;
  #pragma unroll
  for (int h = 0; h < 5; h++){ al[h] = __expf(sc[h] - m); den += al[h]; }
  float inv = 1.f / den;
  float o0 = al[0] * bf2f(zbf[(size_t)an * NC + lane]);
  float o1 = al[0] * bf2f(zbf[(size_t)an * NC + 64 + lane]);
  #pragma unroll
  for (int h = 1; h < 5; h++){
    o0 += al[h] * bf2f(embs[((size_t)(h - 1) * NA + n) * NC + lane]);
    o1 += al[h] * bf2f(embs[((size_t)(h - 1) * NA + n) * NC + 64 + lane]);
  }
  o0 *= inv; o1 *= inv;
  float mx = fmaxf(o0, o1);
  #pragma unroll
  for (int o = 32; o; o >>= 1) mx = fmaxf(mx, __shfl_xor(mx, o));
  float se = __expf(o0 - mx) + __expf(o1 - mx);
  #pragma unroll
  for (int o = 32; o; o >>= 1) se += __shfl_xor(se, o);
  float ls = __logf(se);
  out[(size_t)n * NC + lane]      = o0 - mx - ls;
  out[(size_t)n * NC + 64 + lane] = o1 - mx - ls;
}

// ---------------- launch ----------------

extern "C" void kernel_launch(void* const* d_in, const int* in_sizes, int n_in,
                              void* d_out, int out_size, void* d_ws, size_t ws_size,
                              hipStream_t stream)
{
  const float* x    = (const float*)d_in[0];
  const float* W1   = (const float*)d_in[1];
  const float* W2   = (const float*)d_in[2];
  const float* b2   = (const float*)d_in[3];
  const float* Wg   = (const float*)d_in[4];
  const float* Wa   = (const float*)d_in[5];
  const float* ba   = (const float*)d_in[6];
  const float* va   = (const float*)d_in[7];
  const float* adjv = (const float*)d_in[8];
  const int*   adji = (const int*)d_in[9];
  const int*   idx  = (const int*)d_in[10];
  float* out = (float*)d_out;
  (void)in_sizes; (void)n_in; (void)out_size; (void)ws_size;

  char* w = (char*)d_ws;
  auto alloc = [&](size_t b) -> char* { char* p = w; w += (b + 255) & ~(size_t)255; return p; };
  unsigned short* Scr1 = (unsigned short*)alloc((size_t)NA * NFEAT * 2);  // 51.2MB: Xbf -> binned -> embs
  unsigned short* Hbuf = (unsigned short*)alloc((size_t)NA * HID * 2);    // 51.2MB: GEMM1 out -> aggbf
  unsigned short* W1T  = (unsigned short*)alloc((size_t)HID * NFEAT * 2);
  unsigned short* W2T  = (unsigned short*)alloc((size_t)NC * HID * 2);
  unsigned short* WgT  = (unsigned short*)alloc((size_t)NC * NC * 2);
  unsigned short* WaT  = (unsigned short*)alloc((size_t)NC * NC * 2);
  unsigned short* WfuseT = (unsigned short*)alloc((size_t)AH * NC * 2);
  unsigned short* zbf  = (unsigned short*)alloc((size_t)NA * NC * 2);
  float*          ZW   = (float*)alloc((size_t)NA * NC * 4);
  int* fill  = (int*)alloc((size_t)NHOP * NBUCK * 4);
  int* bbase = (int*)alloc((size_t)NHOP * NBUCK * 4);
  int* offs  = (int*)alloc(((size_t)NHOP * NA + 1) * 4);
  long long* pvc = (long long*)alloc((size_t)NHOP * NE * 8);              // CSR records {val,col}
  unsigned short* Xbf   = Scr1;                  // x bf16 (consumed by GEMM1)
  long long* binned     = (long long*)Scr1;      // live binA..binB (after GEMM1)
  unsigned short* embs  = Scr1;                  // [4][NA][NC] bf16 (after binB)
  unsigned short* aggbf = Hbuf;                  // [4][NA][NC] bf16 (after GEMM2)
  unsigned short* EW    = (unsigned short*)pvc;  // [4][NA][64] bf16 (pvc dead after gather)

  // x cast + merged weight prep
  cast_x_kernel<<<dim3((NA * NFEAT / 4 + 255) / 256), 256, 0, stream>>>(x, Xbf, NA * NFEAT / 4);
  prep_kernel<<<dim3(1440), 256, 0, stream>>>(W1, W2, Wg, Wa, W1T, W2T, WgT, WaT, WfuseT);

  // z = relu(x@W1)@W2 + b2   (bf16 z only; f32 z eliminated)
  gemm_bt<0, 1><<<dim3(1568, 1, 1), 256, 0, stream>>>(Xbf, W1T, Hbuf, nullptr, NA, HID, NFEAT);
  gemm_bt<1, 0><<<dim3(391, 1, 1), 256, 0, stream>>>(Hbuf, W2T, zbf, b2, NA, NC, HID);

  // CSR build: bin -> scan -> fine sort (Xbf dead now; binned aliases it)
  hipMemsetAsync(fill, 0, (size_t)NHOP * NBUCK * 4, stream);
  binA_kernel<<<dim3((NE + 2047) / 2048, NHOP), 256, 0, stream>>>(adji, adjv, fill, binned);
  bscan_kernel<<<dim3(1), 1024, 0, stream>>>(fill, bbase, offs);
  binB_kernel<<<dim3(NBUCK, NHOP), 256, 0, stream>>>(fill, bbase, binned, offs, pvc);

  // aggregate (r8 winner), then one merged 9-slice GEMM launch
  gather_kernel<<<dim3(NA / GR, NHOP), 256, 0, stream>>>(offs, pvc, zbf, aggbf);
  gemm_sweep<<<dim3(391, 1, 9), 256, 0, stream>>>(aggbf, zbf, WgT, WfuseT, WaT, embs, EW, ZW);

  // fused softmax-attention + log_softmax
  final_kernel<<<dim3(NA / 4), 256, 0, stream>>>(zbf, embs, ZW, EW, ba, va, idx, out);
}

// Round 11
// 337.174 us; speedup vs baseline: 1.5280x; 1.0119x over previous
//
#include <hip/hip_runtime.h>

#define NA    50000
#define NFEAT 512
#define HID   512
#define NC    128
#define AH    64
#define NE    800000
#define NHOP  4
#define NBUCK 196      // ceil(NA/256) buckets of 256 rows
#define CAPB  5120     // per-bucket capacity (mean 4082 -> 16 sigma headroom)

typedef __bf16 bf16x8 __attribute__((ext_vector_type(8)));
typedef float  f32x4  __attribute__((ext_vector_type(4)));

__device__ __forceinline__ unsigned short f2bf(float f){
  union { float f; unsigned u; } a; a.f = f;
  return (unsigned short)((a.u + 0x7fffu + ((a.u >> 16) & 1u)) >> 16);  // RNE
}
__device__ __forceinline__ float bf2f(unsigned short h){
  union { unsigned u; float f; } a; a.u = ((unsigned)h) << 16;
  return a.f;
}
__device__ __forceinline__ float uasf(unsigned u){
  union { unsigned u; float f; } a; a.u = u;
  return a.f;
}
__device__ __forceinline__ float tanh_fast(float x){
  x = fminf(15.f, fmaxf(-15.f, x));
  float e = __expf(2.f * x);
  return (e - 1.f) / (e + 1.f);
}

__device__ __forceinline__ void g2l16(const void* g, void* l){
  __builtin_amdgcn_global_load_lds(
      (const __attribute__((address_space(1))) void*)g,
      (__attribute__((address_space(3))) void*)l, 16, 0, 0);
}

// ---------------- x cast ----------------

__global__ void cast_x_kernel(const float* __restrict__ in, unsigned short* __restrict__ out, int n4){
  int i = blockIdx.x * 256 + threadIdx.x;
  if (i >= n4) return;
  float4 v = reinterpret_cast<const float4*>(in)[i];
  ushort4 o; o.x = f2bf(v.x); o.y = f2bf(v.y); o.z = f2bf(v.z); o.w = f2bf(v.w);
  reinterpret_cast<ushort4*>(out)[i] = o;
}

// ---------------- merged weight prep + fill-zero (one launch) ----------------
__global__ void prep_kernel(const float* __restrict__ W1, const float* __restrict__ W2,
                            const float* __restrict__ Wg, const float* __restrict__ Wa,
                            unsigned short* __restrict__ W1T, unsigned short* __restrict__ W2T,
                            unsigned short* __restrict__ WgT, unsigned short* __restrict__ WaT,
                            unsigned short* __restrict__ WfuseT, int* __restrict__ fill){
  const int b = blockIdx.x, tid = threadIdx.x;
  if (b < 1024){
    int i = b * 256 + tid;                       // 262144: W1T [512][512] = W1^T
    int n = i >> 9, k = i & 511;
    W1T[i] = f2bf(W1[(size_t)k * HID + n]);
  } else if (b < 1280){
    int i = (b - 1024) * 256 + tid;              // 65536: W2T [128][512] = W2^T
    int n = i >> 9, k = i & 511;
    W2T[i] = f2bf(W2[(size_t)k * NC + n]);
  } else if (b < 1344){
    int i = (b - 1280) * 256 + tid;              // 16384: WgT [128][128] = Wg^T
    int n = i >> 7, k = i & 127;
    WgT[i] = f2bf(Wg[(size_t)k * NC + n]);
  } else if (b < 1408){
    int i = (b - 1344) * 256 + tid;              // 16384: WaT packed [Wa_top|Wa_bot]
    int n = i >> 7, k = i & 127;
    float v = (n < 64) ? Wa[(size_t)k * AH + n] : Wa[(size_t)(128 + k) * AH + (n - 64)];
    WaT[i] = f2bf(v);
  } else if (b < 1440){
    int i = (b - 1408) * 256 + tid;              // 8192: Wfuse[j][n] = sum_k Wa_bot[k][j]*Wg[n][k]
    int j = i >> 7, n = i & 127;
    float s = 0.f;
    for (int k = 0; k < 128; k++)
      s += Wa[(size_t)(128 + k) * AH + j] * Wg[(size_t)n * 128 + k];
    WfuseT[i] = f2bf(s);
  } else {
    int i = (b - 1440) * 256 + tid;              // zero fill[784]
    if (i < NHOP * NBUCK) fill[i] = 0;
  }
}

// ---------------- bf16 MFMA GEMM:  C = A[M,K] x BT[N,K]^T ----------------
// OP: 0 relu->bf16   1 +bias->bf16
// SWZ: XCD-affine dispatch (4 col-blocks of a row-block on one XCD)
template<int OP, int SWZ>
__global__ __launch_bounds__(256) void gemm_bt(
    const unsigned short* __restrict__ A, const unsigned short* __restrict__ BT,
    unsigned short* __restrict__ Cb, const float* __restrict__ bias,
    int M, int N, int K)
{
  int row0, col0;
  if (SWZ){
    const int xcd = blockIdx.x & 7, slot = blockIdx.x >> 3;
    const int r = xcd * 49 + (slot >> 2);
    if (r >= 391) return;
    row0 = r * 128; col0 = (slot & 3) * 128;
  } else {
    row0 = blockIdx.x * 128; col0 = blockIdx.y * 128;
  }
  __shared__ unsigned short As[128 * 32];
  __shared__ unsigned short Bs[128 * 32];
  const int tid = threadIdx.x;
  const int wave = tid >> 6, lane = tid & 63;
  const int wr = (wave >> 1) * 64, wc = (wave & 1) * 64;
  f32x4 acc[4][4];
  #pragma unroll
  for (int m = 0; m < 4; m++)
    #pragma unroll
    for (int n = 0; n < 4; n++) acc[m][n] = (f32x4){0.f, 0.f, 0.f, 0.f};
  const int lrow = lane >> 2, lk = (lane & 3) * 8;

  for (int k0 = 0; k0 < K; k0 += 32){
    __syncthreads();
    #pragma unroll
    for (int j = 0; j < 2; j++){
      const int rb = (wave * 2 + j) * 16;       // wave-uniform LDS base row
      const int ra = rb + lrow;
      int gr = row0 + ra; gr = gr < M ? gr : M - 1;
      g2l16(A + (size_t)gr * K + k0 + lk, As + rb * 32);
      int gc = col0 + ra; gc = gc < N ? gc : N - 1;
      g2l16(BT + (size_t)gc * K + k0 + lk, Bs + rb * 32);
    }
    __syncthreads();
    bf16x8 af[4], bfr[4];
    #pragma unroll
    for (int m = 0; m < 4; m++)
      af[m] = *reinterpret_cast<const bf16x8*>(&As[(wr + m * 16 + (lane & 15)) * 32 + (lane >> 4) * 8]);
    #pragma unroll
    for (int n = 0; n < 4; n++)
      bfr[n] = *reinterpret_cast<const bf16x8*>(&Bs[(wc + n * 16 + (lane & 15)) * 32 + (lane >> 4) * 8]);
    #pragma unroll
    for (int m = 0; m < 4; m++)
      #pragma unroll
      for (int n = 0; n < 4; n++)
        acc[m][n] = __builtin_amdgcn_mfma_f32_16x16x32_bf16(af[m], bfr[n], acc[m][n], 0, 0, 0);
  }

  const int rbase = row0 + wr + (lane >> 4) * 4;
  const int cbase = col0 + wc + (lane & 15);
  #pragma unroll
  for (int m = 0; m < 4; m++){
    #pragma unroll
    for (int n = 0; n < 4; n++){
      const int col = cbase + n * 16;
      #pragma unroll
      for (int i = 0; i < 4; i++){
        const int row = rbase + m * 16 + i;
        if (row < M && col < N){
          float v = acc[m][n][i];
          if (OP == 0){ v = v > 0.f ? v : 0.f; }
          else        { v += bias[col]; }
          Cb[(size_t)row * N + col] = f2bf(v);
        }
      }
    }
  }
}

// ---------------- merged small-GEMM sweep (9 slices, K=128, M=NA) ----------------
// z 0-3: embs_h = agg_h @ Wg      (N=128, 128-row tiles)
// z 4-7: EWf_h  = agg_h @ Wfuse   (N=64,  256-row tiles, full wave util)
// z 8  : ZWb    = zbf @ [Wa_top|Wa_bot]  (N=128, bf16 out)
__global__ __launch_bounds__(256) void gemm_sweep(
    const unsigned short* __restrict__ aggbf, const unsigned short* __restrict__ zbf,
    const unsigned short* __restrict__ WgT, const unsigned short* __restrict__ WfuseT,
    const unsigned short* __restrict__ WaT,
    unsigned short* __restrict__ embs, unsigned short* __restrict__ EW,
    unsigned short* __restrict__ ZWb)
{
  const int zi = blockIdx.z;
  const bool ew = (zi >= 4 && zi < 8);
  const int row0 = blockIdx.x * (ew ? 256 : 128);
  if (row0 >= NA) return;                        // trims ew grid to 196 blocks
  const unsigned short* A; const unsigned short* BT; unsigned short* Cb; int N;
  if (zi < 4)      { A = aggbf + (size_t)zi * NA * NC;       BT = WgT;    Cb = embs + (size_t)zi * NA * NC; N = 128; }
  else if (ew)     { A = aggbf + (size_t)(zi - 4) * NA * NC; BT = WfuseT; Cb = EW + (size_t)(zi - 4) * NA * AH; N = 64; }
  else             { A = zbf;                                BT = WaT;    Cb = ZWb; N = 128; }

  __shared__ unsigned short As[256 * 32];
  __shared__ unsigned short Bs[128 * 32];
  const int tid = threadIdx.x;
  const int wave = tid >> 6, lane = tid & 63;
  const int wr = ew ? wave * 64 : (wave >> 1) * 64;
  const int wc = ew ? 0 : (wave & 1) * 64;
  f32x4 acc[4][4];
  #pragma unroll
  for (int m = 0; m < 4; m++)
    #pragma unroll
    for (int n = 0; n < 4; n++) acc[m][n] = (f32x4){0.f, 0.f, 0.f, 0.f};
  const int lrow = lane >> 2, lk = (lane & 3) * 8;

  for (int k0 = 0; k0 < 128; k0 += 32){
    __syncthreads();
    if (ew){
      #pragma unroll
      for (int j = 0; j < 4; j++){               // 256 A rows
        const int rb = (wave * 4 + j) * 16;
        int gr = row0 + rb + lrow; gr = gr < NA ? gr : NA - 1;
        g2l16(A + (size_t)gr * 128 + k0 + lk, As + rb * 32);
      }
      {                                          // 64 B rows (one issue/wave)
        const int rb = wave * 16;
        int gc = rb + lrow; gc = gc < 64 ? gc : 63;
        g2l16(BT + (size_t)gc * 128 + k0 + lk, Bs + rb * 32);
      }
    } else {
      #pragma unroll
      for (int j = 0; j < 2; j++){
        const int rb = (wave * 2 + j) * 16;
        int gr = row0 + rb + lrow; gr = gr < NA ? gr : NA - 1;
        g2l16(A + (size_t)gr * 128 + k0 + lk, As + rb * 32);
        int gc = rb + lrow; gc = gc < N ? gc : N - 1;
        g2l16(BT + (size_t)gc * 128 + k0 + lk, Bs + rb * 32);
      }
    }
    __syncthreads();
    bf16x8 bfr[4];
    #pragma unroll
    for (int n = 0; n < 4; n++)
      bfr[n] = *reinterpret_cast<const bf16x8*>(&Bs[(wc + n * 16 + (lane & 15)) * 32 + (lane >> 4) * 8]);
    #pragma unroll
    for (int m = 0; m < 4; m++){
      bf16x8 a = *reinterpret_cast<const bf16x8*>(&As[(wr + m * 16 + (lane & 15)) * 32 + (lane >> 4) * 8]);
      #pragma unroll
      for (int n = 0; n < 4; n++)
        acc[m][n] = __builtin_amdgcn_mfma_f32_16x16x32_bf16(a, bfr[n], acc[m][n], 0, 0, 0);
    }
  }

  const int rbase = row0 + wr + (lane >> 4) * 4;
  const int cbase = wc + (lane & 15);
  #pragma unroll
  for (int m = 0; m < 4; m++){
    #pragma unroll
    for (int n = 0; n < 4; n++){
      const int col = cbase + n * 16;
      #pragma unroll
      for (int i = 0; i < 4; i++){
        const int row = rbase + m * 16 + i;
        if (row < NA && col < N)
          Cb[(size_t)row * N + col] = f2bf(acc[m][n][i]);
      }
    }
  }
}

// ---------------- two-level binned CSR build ----------------
// binA record: lo32 = val bits, hi32 = (localrow<<17)|col
__global__ __launch_bounds__(256) void binA_kernel(
    const int* __restrict__ adji, const float* __restrict__ adjv,
    int* __restrict__ fill, long long* __restrict__ binned)
{
  const int h = blockIdx.y, tid = threadIdx.x;
  const int e0 = blockIdx.x * 2048;
  __shared__ int lhist[NBUCK], lbase[NBUCK], lfill[NBUCK];
  for (int i = tid; i < NBUCK; i += 256){ lhist[i] = 0; lfill[i] = 0; }
  __syncthreads();
  int rr[8]; unsigned hh[8]; float vv[8];
  #pragma unroll
  for (int k = 0; k < 8; k++){
    int e = e0 + k * 256 + tid;
    bool ok = e < NE;
    int r = ok ? adji[(size_t)h * 2 * NE + e] : -1;
    int c = ok ? adji[(size_t)h * 2 * NE + NE + e] : 0;
    vv[k] = ok ? adjv[(size_t)h * NE + e] : 0.f;
    rr[k] = r;
    hh[k] = ((unsigned)(r & 255) << 17) | (unsigned)c;
    if (ok) atomicAdd(&lhist[r >> 8], 1);
  }
  __syncthreads();
  if (tid < NBUCK) lbase[tid] = atomicAdd(&fill[h * NBUCK + tid], lhist[tid]);
  __syncthreads();
  #pragma unroll
  for (int k = 0; k < 8; k++){
    if (rr[k] >= 0){
      int b = rr[k] >> 8;
      int p = lbase[b] + atomicAdd(&lfill[b], 1);
      if (p < CAPB)
        binned[((size_t)(h * NBUCK + b)) * CAPB + p] =
            ((long long)hh[k] << 32) | (unsigned)__float_as_int(vv[k]);
    }
  }
}

__global__ __launch_bounds__(1024) void bscan_kernel(const int* __restrict__ fill,
                                                     int* __restrict__ bbase, int* __restrict__ offs){
  __shared__ int tmp[1024];
  int tid = threadIdx.x;
  int v = (tid < NHOP * NBUCK) ? fill[tid] : 0;
  tmp[tid] = v; __syncthreads();
  for (int o = 1; o < 1024; o <<= 1){
    int t = (tid >= o) ? tmp[tid - o] : 0;
    __syncthreads();
    tmp[tid] += t;
    __syncthreads();
  }
  if (tid < NHOP * NBUCK) bbase[tid] = tmp[tid] - v;
  if (tid == 0) offs[NHOP * NA] = NHOP * NE;
}

// binB output record: lo32 = val bits, hi32 = col<<6 (z row dword offset, gather adds lane)
__global__ __launch_bounds__(256) void binB_kernel(
    const int* __restrict__ fill, const int* __restrict__ bbase,
    const long long* __restrict__ binned,
    int* __restrict__ offs, long long* __restrict__ pvc)
{
  const int b = blockIdx.x, h = blockIdx.y, tid = threadIdx.x;
  const int hb = h * NBUCK + b;
  const int cnt = min(fill[hb], CAPB);
  const long long* src = binned + (size_t)hb * CAPB;
  const int gbase = bbase[hb];
  const int rowbase = b << 8;
  const int nrows = min(256, NA - rowbase);
  __shared__ long long sdata[CAPB];
  __shared__ int lhist[256], lpre[256], lfill2[256];
  lhist[tid] = 0; lfill2[tid] = 0;
  __syncthreads();
  for (int p = tid; p < cnt; p += 256)
    atomicAdd(&lhist[(unsigned)(src[p] >> 32) >> 17], 1);
  __syncthreads();
  int v = lhist[tid]; lpre[tid] = v; __syncthreads();
  for (int o = 1; o < 256; o <<= 1){
    int t = (tid >= o) ? lpre[tid - o] : 0;
    __syncthreads();
    lpre[tid] += t;
    __syncthreads();
  }
  int excl = lpre[tid] - v;
  if (tid < nrows) offs[h * NA + rowbase + tid] = gbase + excl;
  lpre[tid] = excl;
  __syncthreads();
  for (int p = tid; p < cnt; p += 256){
    long long rec = src[p];
    unsigned hi = (unsigned)(rec >> 32);
    int lr = hi >> 17;
    long long out = (rec & 0xffffffffLL) | ((long long)((hi & 0x1ffffu) << 6) << 32);
    int pos = lpre[lr] + atomicAdd(&lfill2[lr], 1);
    if (pos < CAPB) sdata[pos] = out;
    else            pvc[(size_t)gbase + pos] = out;
  }
  __syncthreads();
  for (int p = tid; p < cnt; p += 256)
    pvc[(size_t)gbase + p] = sdata[p];
}

// ---------------- single-pass 128-channel gather, wave-per-row (r8 winner) ----------------
// One wave per row; lane owns channel pair -> one dword z-load per lane per
// edge (256B/wave). Records staged to LDS by coalesced wave load (same-wave,
// no barrier), consumed wave-uniform as int4 (2 records) x2 per iter; unroll 4
// -> 16 z loads in flight. col pre-shifted <<6 in binB (addr = hi + lane).
// Empirically optimal vs all channel-tiled variants (r2/r4/r9 latency-bound).
#define GR 4
__global__ __launch_bounds__(256) void gather_kernel(
    const int* __restrict__ offs, const long long* __restrict__ pvc,
    const unsigned short* __restrict__ zbf, unsigned short* __restrict__ aggbf)
{
  const int h = blockIdx.y;
  const int w = threadIdx.x >> 6, lane = threadIdx.x & 63;
  const int row = blockIdx.x * GR + w;
  const int base = h * NA + row;
  const int s = offs[base], e = offs[base + 1];
  __shared__ alignas(16) long long srec[GR][64];
  const unsigned* z32 = (const unsigned*)zbf;   // [NA][64] dwords (2 bf16 each)
  const int4* sr2 = (const int4*)&srec[w][0];
  float a0 = 0.f, a1 = 0.f, b0 = 0.f, b1 = 0.f;
  for (int p0 = s; p0 < e; p0 += 64){
    long long r = 0;
    if (p0 + lane < e) r = __builtin_nontemporal_load(&pvc[p0 + lane]);
    srec[w][lane] = r;                          // all 64 lanes write -> padding stays 0
    const int quads = (min(64, e - p0) + 3) >> 2;
    #pragma unroll 4
    for (int q = 0; q < quads; q++){
      int4 ra = sr2[2 * q], rb = sr2[2 * q + 1];  // 4 records, wave-uniform broadcast
      unsigned z0 = z32[(unsigned)ra.y + lane];
      unsigned z1 = z32[(unsigned)ra.w + lane];
      unsigned z2 = z32[(unsigned)rb.y + lane];
      unsigned z3 = z32[(unsigned)rb.w + lane];
      float v0 = uasf((unsigned)ra.x), v1 = uasf((unsigned)ra.z);
      float v2 = uasf((unsigned)rb.x), v3 = uasf((unsigned)rb.z);
      a0 += v0 * uasf(z0 << 16); a1 += v0 * uasf(z0 & 0xffff0000u);
      b0 += v1 * uasf(z1 << 16); b1 += v1 * uasf(z1 & 0xffff0000u);
      a0 += v2 * uasf(z2 << 16); a1 += v2 * uasf(z2 & 0xffff0000u);
      b0 += v3 * uasf(z3 << 16); b1 += v3 * uasf(z3 & 0xffff0000u);
    }
  }
  ushort2 o; o.x = f2bf(a0 + b0); o.y = f2bf(a1 + b1);
  *reinterpret_cast<ushort2*>(aggbf + (size_t)base * NC + lane * 2) = o;
}

// ---------------- fused attention epilogue (bf16 anchor + bf16 ZW) ----------------
__global__ __launch_bounds__(256) void final_kernel(
    const unsigned short* __restrict__ zbf, const unsigned short* __restrict__ embs,
    const unsigned short* __restrict__ ZWb, const unsigned short* __restrict__ EW,
    const float* __restrict__ ba, const float* __restrict__ va,
    const int* __restrict__ idx, float* __restrict__ out)
{
  int tid = threadIdx.x, wave = tid >> 6, lane = tid & 63;
  int n = blockIdx.x * 4 + wave;
  if (n >= NA) return;
  int an = idx[n];
  float qa = bf2f(ZWb[(size_t)an * NC + lane]) + ba[lane];
  float vaj = va[lane];
  float sc[5];
  {
    float s0 = bf2f(ZWb[(size_t)an * NC + 64 + lane]);
    float t = tanh_fast(qa + s0) * vaj;
    #pragma unroll
    for (int o = 32; o; o >>= 1) t += __shfl_xor(t, o);
    sc[0] = t;
  }
  #pragma unroll
  for (int h = 1; h < 5; h++){
    float sh = bf2f(EW[((size_t)(h - 1) * NA + n) * AH + lane]);
    float t = tanh_fast(qa + sh) * vaj;
    #pragma unroll
    for (int o = 32; o; o >>= 1) t += __shfl_xor(t, o);
    sc[h] = t;
  }
  float m = sc[0];
  #pragma unroll
  for (int h = 1; h < 5; h++) m = fmaxf(m, sc[h]);
  float al[5], den = 0.f;
  #pragma unroll
  for (int h = 0; h < 5; h++){ al[h] = __expf(sc[h] - m); den += al[h]; }
  float inv = 1.f / den;
  float o0 = al[0] * bf2f(zbf[(size_t)an * NC + lane]);
  float o1 = al[0] * bf2f(zbf[(size_t)an * NC + 64 + lane]);
  #pragma unroll
  for (int h = 1; h < 5; h++){
    o0 += al[h] * bf2f(embs[((size_t)(h - 1) * NA + n) * NC + lane]);
    o1 += al[h] * bf2f(embs[((size_t)(h - 1) * NA + n) * NC + 64 + lane]);
  }
  o0 *= inv; o1 *= inv;
  float mx = fmaxf(o0, o1);
  #pragma unroll
  for (int o = 32; o; o >>= 1) mx = fmaxf(mx, __shfl_xor(mx, o));
  float se = __expf(o0 - mx) + __expf(o1 - mx);
  #pragma unroll
  for (int o = 32; o; o >>= 1) se += __shfl_xor(se, o);
  float ls = __logf(se);
  out[(size_t)n * NC + lane]      = o0 - mx - ls;
  out[(size_t)n * NC + 64 + lane] = o1 - mx - ls;
}

// ---------------- launch ----------------

extern "C" void kernel_launch(void* const* d_in, const int* in_sizes, int n_in,
                              void* d_out, int out_size, void* d_ws, size_t ws_size,
                              hipStream_t stream)
{
  const float* x    = (const float*)d_in[0];
  const float* W1   = (const float*)d_in[1];
  const float* W2   = (const float*)d_in[2];
  const float* b2   = (const float*)d_in[3];
  const float* Wg   = (const float*)d_in[4];
  const float* Wa   = (const float*)d_in[5];
  const float* ba   = (const float*)d_in[6];
  const float* va   = (const float*)d_in[7];
  const float* adjv = (const float*)d_in[8];
  const int*   adji = (const int*)d_in[9];
  const int*   idx  = (const int*)d_in[10];
  float* out = (float*)d_out;
  (void)in_sizes; (void)n_in; (void)out_size; (void)ws_size;

  char* w = (char*)d_ws;
  auto alloc = [&](size_t b) -> char* { char* p = w; w += (b + 255) & ~(size_t)255; return p; };
  unsigned short* Scr1 = (unsigned short*)alloc((size_t)NA * NFEAT * 2);  // 51.2MB: Xbf -> binned -> embs
  unsigned short* Hbuf = (unsigned short*)alloc((size_t)NA * HID * 2);    // 51.2MB: GEMM1 out -> aggbf
  unsigned short* W1T  = (unsigned short*)alloc((size_t)HID * NFEAT * 2);
  unsigned short* W2T  = (unsigned short*)alloc((size_t)NC * HID * 2);
  unsigned short* WgT  = (unsigned short*)alloc((size_t)NC * NC * 2);
  unsigned short* WaT  = (unsigned short*)alloc((size_t)NC * NC * 2);
  unsigned short* WfuseT = (unsigned short*)alloc((size_t)AH * NC * 2);
  unsigned short* zbf  = (unsigned short*)alloc((size_t)NA * NC * 2);
  unsigned short* ZWb  = (unsigned short*)alloc((size_t)NA * NC * 2);
  int* fill  = (int*)alloc((size_t)NHOP * NBUCK * 4);
  int* bbase = (int*)alloc((size_t)NHOP * NBUCK * 4);
  int* offs  = (int*)alloc(((size_t)NHOP * NA + 1) * 4);
  long long* pvc = (long long*)alloc((size_t)NHOP * NE * 8);              // CSR records {val, col<<6}
  unsigned short* Xbf   = Scr1;                  // x bf16 (consumed by GEMM1)
  long long* binned     = (long long*)Scr1;      // live binA..binB (after GEMM1)
  unsigned short* embs  = Scr1;                  // [4][NA][NC] bf16 (after binB)
  unsigned short* aggbf = Hbuf;                  // [4][NA][NC] bf16 (after GEMM2)
  unsigned short* EW    = (unsigned short*)pvc;  // [4][NA][64] bf16 (pvc dead after gather)

  // x cast + merged weight prep (also zeroes fill)
  cast_x_kernel<<<dim3((NA * NFEAT / 4 + 255) / 256), 256, 0, stream>>>(x, Xbf, NA * NFEAT / 4);
  prep_kernel<<<dim3(1444), 256, 0, stream>>>(W1, W2, Wg, Wa, W1T, W2T, WgT, WaT, WfuseT, fill);

  // z = relu(x@W1)@W2 + b2   (bf16 z only)
  gemm_bt<0, 1><<<dim3(1568, 1, 1), 256, 0, stream>>>(Xbf, W1T, Hbuf, nullptr, NA, HID, NFEAT);
  gemm_bt<1, 0><<<dim3(391, 1, 1), 256, 0, stream>>>(Hbuf, W2T, zbf, b2, NA, NC, HID);

  // CSR build: bin -> scan -> fine sort (Xbf dead now; binned aliases it)
  binA_kernel<<<dim3((NE + 2047) / 2048, NHOP), 256, 0, stream>>>(adji, adjv, fill, binned);
  bscan_kernel<<<dim3(1), 1024, 0, stream>>>(fill, bbase, offs);
  binB_kernel<<<dim3(NBUCK, NHOP), 256, 0, stream>>>(fill, bbase, binned, offs, pvc);

  // aggregate (r8 winner), then one merged 9-slice GEMM launch
  gather_kernel<<<dim3(NA / GR, NHOP), 256, 0, stream>>>(offs, pvc, zbf, aggbf);
  gemm_sweep<<<dim3(391, 1, 9), 256, 0, stream>>>(aggbf, zbf, WgT, WfuseT, WaT, embs, EW, ZWb);

  // fused softmax-attention + log_softmax
  final_kernel<<<dim3(NA / 4), 256, 0, stream>>>(zbf, embs, ZWb, EW, ba, va, idx, out);
}

// Round 12
// 336.729 us; speedup vs baseline: 1.5300x; 1.0013x over previous
//
#include <hip/hip_runtime.h>

#define NA    50000
#define NFEAT 512
#define HID   512
#define NC    128
#define AH    64
#define NE    800000
#define NHOP  4
#define NBUCK 196      // ceil(NA/256) buckets of 256 rows
#define CAPB  5120     // per-bucket capacity (mean 4082 -> 16 sigma headroom)

typedef __bf16 bf16x8 __attribute__((ext_vector_type(8)));
typedef float  f32x4  __attribute__((ext_vector_type(4)));

__device__ __forceinline__ unsigned short f2bf(float f){
  union { float f; unsigned u; } a; a.f = f;
  return (unsigned short)((a.u + 0x7fffu + ((a.u >> 16) & 1u)) >> 16);  // RNE
}
__device__ __forceinline__ float bf2f(unsigned short h){
  union { unsigned u; float f; } a; a.u = ((unsigned)h) << 16;
  return a.f;
}
__device__ __forceinline__ float uasf(unsigned u){
  union { unsigned u; float f; } a; a.u = u;
  return a.f;
}
__device__ __forceinline__ float tanh_fast(float x){
  x = fminf(15.f, fmaxf(-15.f, x));
  float e = __expf(2.f * x);
  return (e - 1.f) / (e + 1.f);
}

__device__ __forceinline__ void g2l16(const void* g, void* l){
  __builtin_amdgcn_global_load_lds(
      (const __attribute__((address_space(1))) void*)g,
      (__attribute__((address_space(3))) void*)l, 16, 0, 0);
}

// ---------------- merged weight prep + fill-zero (one launch) ----------------
__global__ void prep_kernel(const float* __restrict__ W1, const float* __restrict__ W2,
                            const float* __restrict__ Wg, const float* __restrict__ Wa,
                            unsigned short* __restrict__ W1T, unsigned short* __restrict__ W2T,
                            unsigned short* __restrict__ WgT, unsigned short* __restrict__ WaT,
                            unsigned short* __restrict__ WfuseT, int* __restrict__ fill){
  const int b = blockIdx.x, tid = threadIdx.x;
  if (b < 1024){
    int i = b * 256 + tid;                       // 262144: W1T [512][512] = W1^T
    int n = i >> 9, k = i & 511;
    W1T[i] = f2bf(W1[(size_t)k * HID + n]);
  } else if (b < 1280){
    int i = (b - 1024) * 256 + tid;              // 65536: W2T [128][512] = W2^T
    int n = i >> 9, k = i & 511;
    W2T[i] = f2bf(W2[(size_t)k * NC + n]);
  } else if (b < 1344){
    int i = (b - 1280) * 256 + tid;              // 16384: WgT [128][128] = Wg^T
    int n = i >> 7, k = i & 127;
    WgT[i] = f2bf(Wg[(size_t)k * NC + n]);
  } else if (b < 1408){
    int i = (b - 1344) * 256 + tid;              // 16384: WaT packed [Wa_top|Wa_bot]
    int n = i >> 7, k = i & 127;
    float v = (n < 64) ? Wa[(size_t)k * AH + n] : Wa[(size_t)(128 + k) * AH + (n - 64)];
    WaT[i] = f2bf(v);
  } else if (b < 1440){
    int i = (b - 1408) * 256 + tid;              // 8192: Wfuse[j][n] = sum_k Wa_bot[k][j]*Wg[n][k]
    int j = i >> 7, n = i & 127;
    float s = 0.f;
    for (int k = 0; k < 128; k++)
      s += Wa[(size_t)(128 + k) * AH + j] * Wg[(size_t)n * 128 + k];
    WfuseT[i] = f2bf(s);
  } else {
    int i = (b - 1440) * 256 + tid;              // zero fill[784]
    if (i < NHOP * NBUCK) fill[i] = 0;
  }
}

// ---------------- bf16 MFMA GEMM:  C = A[M,K] x BT[N,K]^T ----------------
// OP: 0 relu->bf16   1 +bias->bf16
// SWZ: XCD-affine dispatch (4 col-blocks of a row-block on one XCD)
// AF32: A is f32 in global; staged via regs (load f32 -> cvt bf16 -> ds_write_b128
//       into the SAME bf16 LDS layout as the g2l16 path; write addr = lane*16,
//       conflict-free). Kills the separate cast_x pass (r7's f32-LDS attempt
//       failed on 2x LDS + 16-way conflicts; this keeps LDS bf16 + 8KB).
template<int OP, int SWZ, int AF32>
__global__ __launch_bounds__(256) void gemm_bt(
    const void* __restrict__ Avoid, const unsigned short* __restrict__ BT,
    unsigned short* __restrict__ Cb, const float* __restrict__ bias,
    int M, int N, int K)
{
  int row0, col0;
  if (SWZ){
    const int xcd = blockIdx.x & 7, slot = blockIdx.x >> 3;
    const int r = xcd * 49 + (slot >> 2);
    if (r >= 391) return;
    row0 = r * 128; col0 = (slot & 3) * 128;
  } else {
    row0 = blockIdx.x * 128; col0 = blockIdx.y * 128;
  }
  const unsigned short* A16 = (const unsigned short*)Avoid;
  const float*          A32 = (const float*)Avoid;
  __shared__ unsigned short As[128 * 32];
  __shared__ unsigned short Bs[128 * 32];
  const int tid = threadIdx.x;
  const int wave = tid >> 6, lane = tid & 63;
  const int wr = (wave >> 1) * 64, wc = (wave & 1) * 64;
  f32x4 acc[4][4];
  #pragma unroll
  for (int m = 0; m < 4; m++)
    #pragma unroll
    for (int n = 0; n < 4; n++) acc[m][n] = (f32x4){0.f, 0.f, 0.f, 0.f};
  const int lrow = lane >> 2, lk = (lane & 3) * 8;

  for (int k0 = 0; k0 < K; k0 += 32){
    __syncthreads();
    #pragma unroll
    for (int j = 0; j < 2; j++){
      const int rb = (wave * 2 + j) * 16;       // wave-uniform LDS base row
      const int ra = rb + lrow;
      int gr = row0 + ra; gr = gr < M ? gr : M - 1;
      if (AF32){
        const float* src = A32 + (size_t)gr * K + k0 + lk;
        float4 f0 = *reinterpret_cast<const float4*>(src);
        float4 f1 = *reinterpret_cast<const float4*>(src + 4);
        bf16x8 a;
        a[0] = (__bf16)f0.x; a[1] = (__bf16)f0.y; a[2] = (__bf16)f0.z; a[3] = (__bf16)f0.w;
        a[4] = (__bf16)f1.x; a[5] = (__bf16)f1.y; a[6] = (__bf16)f1.z; a[7] = (__bf16)f1.w;
        *reinterpret_cast<bf16x8*>(&As[ra * 32 + lk]) = a;    // addr = lane*16: linear
      } else {
        g2l16(A16 + (size_t)gr * K + k0 + lk, As + rb * 32);
      }
      int gc = col0 + ra; gc = gc < N ? gc : N - 1;
      g2l16(BT + (size_t)gc * K + k0 + lk, Bs + rb * 32);
    }
    __syncthreads();
    bf16x8 af[4], bfr[4];
    #pragma unroll
    for (int m = 0; m < 4; m++)
      af[m] = *reinterpret_cast<const bf16x8*>(&As[(wr + m * 16 + (lane & 15)) * 32 + (lane >> 4) * 8]);
    #pragma unroll
    for (int n = 0; n < 4; n++)
      bfr[n] = *reinterpret_cast<const bf16x8*>(&Bs[(wc + n * 16 + (lane & 15)) * 32 + (lane >> 4) * 8]);
    #pragma unroll
    for (int m = 0; m < 4; m++)
      #pragma unroll
      for (int n = 0; n < 4; n++)
        acc[m][n] = __builtin_amdgcn_mfma_f32_16x16x32_bf16(af[m], bfr[n], acc[m][n], 0, 0, 0);
  }

  const int rbase = row0 + wr + (lane >> 4) * 4;
  const int cbase = col0 + wc + (lane & 15);
  #pragma unroll
  for (int m = 0; m < 4; m++){
    #pragma unroll
    for (int n = 0; n < 4; n++){
      const int col = cbase + n * 16;
      #pragma unroll
      for (int i = 0; i < 4; i++){
        const int row = rbase + m * 16 + i;
        if (row < M && col < N){
          float v = acc[m][n][i];
          if (OP == 0){ v = v > 0.f ? v : 0.f; }
          else        { v += bias[col]; }
          Cb[(size_t)row * N + col] = f2bf(v);
        }
      }
    }
  }
}

// ---------------- merged small-GEMM sweep (9 slices, K=128, M=NA) ----------------
// z 0-3: embs_h = agg_h @ Wg      (N=128, 128-row tiles)
// z 4-7: EWf_h  = agg_h @ Wfuse   (N=64,  256-row tiles, full wave util)
// z 8  : ZWb    = zbf @ [Wa_top|Wa_bot]  (N=128, bf16 out)
__global__ __launch_bounds__(256) void gemm_sweep(
    const unsigned short* __restrict__ aggbf, const unsigned short* __restrict__ zbf,
    const unsigned short* __restrict__ WgT, const unsigned short* __restrict__ WfuseT,
    const unsigned short* __restrict__ WaT,
    unsigned short* __restrict__ embs, unsigned short* __restrict__ EW,
    unsigned short* __restrict__ ZWb)
{
  const int zi = blockIdx.z;
  const bool ew = (zi >= 4 && zi < 8);
  const int row0 = blockIdx.x * (ew ? 256 : 128);
  if (row0 >= NA) return;                        // trims ew grid to 196 blocks
  const unsigned short* A; const unsigned short* BT; unsigned short* Cb; int N;
  if (zi < 4)      { A = aggbf + (size_t)zi * NA * NC;       BT = WgT;    Cb = embs + (size_t)zi * NA * NC; N = 128; }
  else if (ew)     { A = aggbf + (size_t)(zi - 4) * NA * NC; BT = WfuseT; Cb = EW + (size_t)(zi - 4) * NA * AH; N = 64; }
  else             { A = zbf;                                BT = WaT;    Cb = ZWb; N = 128; }

  __shared__ unsigned short As[256 * 32];
  __shared__ unsigned short Bs[128 * 32];
  const int tid = threadIdx.x;
  const int wave = tid >> 6, lane = tid & 63;
  const int wr = ew ? wave * 64 : (wave >> 1) * 64;
  const int wc = ew ? 0 : (wave & 1) * 64;
  f32x4 acc[4][4];
  #pragma unroll
  for (int m = 0; m < 4; m++)
    #pragma unroll
    for (int n = 0; n < 4; n++) acc[m][n] = (f32x4){0.f, 0.f, 0.f, 0.f};
  const int lrow = lane >> 2, lk = (lane & 3) * 8;

  for (int k0 = 0; k0 < 128; k0 += 32){
    __syncthreads();
    if (ew){
      #pragma unroll
      for (int j = 0; j < 4; j++){               // 256 A rows
        const int rb = (wave * 4 + j) * 16;
        int gr = row0 + rb + lrow; gr = gr < NA ? gr : NA - 1;
        g2l16(A + (size_t)gr * 128 + k0 + lk, As + rb * 32);
      }
      {                                          // 64 B rows (one issue/wave)
        const int rb = wave * 16;
        int gc = rb + lrow; gc = gc < 64 ? gc : 63;
        g2l16(BT + (size_t)gc * 128 + k0 + lk, Bs + rb * 32);
      }
    } else {
      #pragma unroll
      for (int j = 0; j < 2; j++){
        const int rb = (wave * 2 + j) * 16;
        int gr = row0 + rb + lrow; gr = gr < NA ? gr : NA - 1;
        g2l16(A + (size_t)gr * 128 + k0 + lk, As + rb * 32);
        int gc = rb + lrow; gc = gc < N ? gc : N - 1;
        g2l16(BT + (size_t)gc * 128 + k0 + lk, Bs + rb * 32);
      }
    }
    __syncthreads();
    bf16x8 bfr[4];
    #pragma unroll
    for (int n = 0; n < 4; n++)
      bfr[n] = *reinterpret_cast<const bf16x8*>(&Bs[(wc + n * 16 + (lane & 15)) * 32 + (lane >> 4) * 8]);
    #pragma unroll
    for (int m = 0; m < 4; m++){
      bf16x8 a = *reinterpret_cast<const bf16x8*>(&As[(wr + m * 16 + (lane & 15)) * 32 + (lane >> 4) * 8]);
      #pragma unroll
      for (int n = 0; n < 4; n++)
        acc[m][n] = __builtin_amdgcn_mfma_f32_16x16x32_bf16(a, bfr[n], acc[m][n], 0, 0, 0);
    }
  }

  const int rbase = row0 + wr + (lane >> 4) * 4;
  const int cbase = wc + (lane & 15);
  #pragma unroll
  for (int m = 0; m < 4; m++){
    #pragma unroll
    for (int n = 0; n < 4; n++){
      const int col = cbase + n * 16;
      #pragma unroll
      for (int i = 0; i < 4; i++){
        const int row = rbase + m * 16 + i;
        if (row < NA && col < N)
          Cb[(size_t)row * N + col] = f2bf(acc[m][n][i]);
      }
    }
  }
}

// ---------------- two-level binned CSR build ----------------
// binA record: lo32 = val bits, hi32 = (localrow<<17)|col
__global__ __launch_bounds__(256) void binA_kernel(
    const int* __restrict__ adji, const float* __restrict__ adjv,
    int* __restrict__ fill, long long* __restrict__ binned)
{
  const int h = blockIdx.y, tid = threadIdx.x;
  const int e0 = blockIdx.x * 2048;
  __shared__ int lhist[NBUCK], lbase[NBUCK], lfill[NBUCK];
  for (int i = tid; i < NBUCK; i += 256){ lhist[i] = 0; lfill[i] = 0; }
  __syncthreads();
  int rr[8]; unsigned hh[8]; float vv[8];
  #pragma unroll
  for (int k = 0; k < 8; k++){
    int e = e0 + k * 256 + tid;
    bool ok = e < NE;
    int r = ok ? adji[(size_t)h * 2 * NE + e] : -1;
    int c = ok ? adji[(size_t)h * 2 * NE + NE + e] : 0;
    vv[k] = ok ? adjv[(size_t)h * NE + e] : 0.f;
    rr[k] = r;
    hh[k] = ((unsigned)(r & 255) << 17) | (unsigned)c;
    if (ok) atomicAdd(&lhist[r >> 8], 1);
  }
  __syncthreads();
  if (tid < NBUCK) lbase[tid] = atomicAdd(&fill[h * NBUCK + tid], lhist[tid]);
  __syncthreads();
  #pragma unroll
  for (int k = 0; k < 8; k++){
    if (rr[k] >= 0){
      int b = rr[k] >> 8;
      int p = lbase[b] + atomicAdd(&lfill[b], 1);
      if (p < CAPB)
        binned[((size_t)(h * NBUCK + b)) * CAPB + p] =
            ((long long)hh[k] << 32) | (unsigned)__float_as_int(vv[k]);
    }
  }
}

__global__ __launch_bounds__(1024) void bscan_kernel(const int* __restrict__ fill,
                                                     int* __restrict__ bbase, int* __restrict__ offs){
  __shared__ int tmp[1024];
  int tid = threadIdx.x;
  int v = (tid < NHOP * NBUCK) ? fill[tid] : 0;
  tmp[tid] = v; __syncthreads();
  for (int o = 1; o < 1024; o <<= 1){
    int t = (tid >= o) ? tmp[tid - o] : 0;
    __syncthreads();
    tmp[tid] += t;
    __syncthreads();
  }
  if (tid < NHOP * NBUCK) bbase[tid] = tmp[tid] - v;
  if (tid == 0) offs[NHOP * NA] = NHOP * NE;
}

// binB output record: lo32 = val bits, hi32 = col<<6 (z row dword offset, gather adds lane)
__global__ __launch_bounds__(256) void binB_kernel(
    const int* __restrict__ fill, const int* __restrict__ bbase,
    const long long* __restrict__ binned,
    int* __restrict__ offs, long long* __restrict__ pvc)
{
  const int b = blockIdx.x, h = blockIdx.y, tid = threadIdx.x;
  const int hb = h * NBUCK + b;
  const int cnt = min(fill[hb], CAPB);
  const long long* src = binned + (size_t)hb * CAPB;
  const int gbase = bbase[hb];
  const int rowbase = b << 8;
  const int nrows = min(256, NA - rowbase);
  __shared__ long long sdata[CAPB];
  __shared__ int lhist[256], lpre[256], lfill2[256];
  lhist[tid] = 0; lfill2[tid] = 0;
  __syncthreads();
  for (int p = tid; p < cnt; p += 256)
    atomicAdd(&lhist[(unsigned)(src[p] >> 32) >> 17], 1);
  __syncthreads();
  int v = lhist[tid]; lpre[tid] = v; __syncthreads();
  for (int o = 1; o < 256; o <<= 1){
    int t = (tid >= o) ? lpre[tid - o] : 0;
    __syncthreads();
    lpre[tid] += t;
    __syncthreads();
  }
  int excl = lpre[tid] - v;
  if (tid < nrows) offs[h * NA + rowbase + tid] = gbase + excl;
  lpre[tid] = excl;
  __syncthreads();
  for (int p = tid; p < cnt; p += 256){
    long long rec = src[p];
    unsigned hi = (unsigned)(rec >> 32);
    int lr = hi >> 17;
    long long out = (rec & 0xffffffffLL) | ((long long)((hi & 0x1ffffu) << 6) << 32);
    int pos = lpre[lr] + atomicAdd(&lfill2[lr], 1);
    if (pos < CAPB) sdata[pos] = out;
    else            pvc[(size_t)gbase + pos] = out;
  }
  __syncthreads();
  for (int p = tid; p < cnt; p += 256)
    pvc[(size_t)gbase + p] = sdata[p];
}

// ---------------- single-pass 128-channel gather, wave-per-row (converged) ----------------
#define GR 4
__global__ __launch_bounds__(256) void gather_kernel(
    const int* __restrict__ offs, const long long* __restrict__ pvc,
    const unsigned short* __restrict__ zbf, unsigned short* __restrict__ aggbf)
{
  const int h = blockIdx.y;
  const int w = threadIdx.x >> 6, lane = threadIdx.x & 63;
  const int row = blockIdx.x * GR + w;
  const int base = h * NA + row;
  const int s = offs[base], e = offs[base + 1];
  __shared__ alignas(16) long long srec[GR][64];
  const unsigned* z32 = (const unsigned*)zbf;   // [NA][64] dwords (2 bf16 each)
  const int4* sr2 = (const int4*)&srec[w][0];
  float a0 = 0.f, a1 = 0.f, b0 = 0.f, b1 = 0.f;
  for (int p0 = s; p0 < e; p0 += 64){
    long long r = 0;
    if (p0 + lane < e) r = __builtin_nontemporal_load(&pvc[p0 + lane]);
    srec[w][lane] = r;                          // all 64 lanes write -> padding stays 0
    const int quads = (min(64, e - p0) + 3) >> 2;
    #pragma unroll 4
    for (int q = 0; q < quads; q++){
      int4 ra = sr2[2 * q], rb = sr2[2 * q + 1];  // 4 records, wave-uniform broadcast
      unsigned z0 = z32[(unsigned)ra.y + lane];
      unsigned z1 = z32[(unsigned)ra.w + lane];
      unsigned z2 = z32[(unsigned)rb.y + lane];
      unsigned z3 = z32[(unsigned)rb.w + lane];
      float v0 = uasf((unsigned)ra.x), v1 = uasf((unsigned)ra.z);
      float v2 = uasf((unsigned)rb.x), v3 = uasf((unsigned)rb.z);
      a0 += v0 * uasf(z0 << 16); a1 += v0 * uasf(z0 & 0xffff0000u);
      b0 += v1 * uasf(z1 << 16); b1 += v1 * uasf(z1 & 0xffff0000u);
      a0 += v2 * uasf(z2 << 16); a1 += v2 * uasf(z2 & 0xffff0000u);
      b0 += v3 * uasf(z3 << 16); b1 += v3 * uasf(z3 & 0xffff0000u);
    }
  }
  ushort2 o; o.x = f2bf(a0 + b0); o.y = f2bf(a1 + b1);
  *reinterpret_cast<ushort2*>(aggbf + (size_t)base * NC + lane * 2) = o;
}

// ---------------- fused attention epilogue (bf16 anchor + bf16 ZW) ----------------
__global__ __launch_bounds__(256) void final_kernel(
    const unsigned short* __restrict__ zbf, const unsigned short* __restrict__ embs,
    const unsigned short* __restrict__ ZWb, const unsigned short* __restrict__ EW,
    const float* __restrict__ ba, const float* __restrict__ va,
    const int* __restrict__ idx, float* __restrict__ out)
{
  int tid = threadIdx.x, wave = tid >> 6, lane = tid & 63;
  int n = blockIdx.x * 4 + wave;
  if (n >= NA) return;
  int an = idx[n];
  float qa = bf2f(ZWb[(size_t)an * NC + lane]) + ba[lane];
  float vaj = va[lane];
  float sc[5];
  {
    float s0 = bf2f(ZWb[(size_t)an * NC + 64 + lane]);
    float t = tanh_fast(qa + s0) * vaj;
    #pragma unroll
    for (int o = 32; o; o >>= 1) t += __shfl_xor(t, o);
    sc[0] = t;
  }
  #pragma unroll
  for (int h = 1; h < 5; h++){
    float sh = bf2f(EW[((size_t)(h - 1) * NA + n) * AH + lane]);
    float t = tanh_fast(qa + sh) * vaj;
    #pragma unroll
    for (int o = 32; o; o >>= 1) t += __shfl_xor(t, o);
    sc[h] = t;
  }
  float m = sc[0];
  #pragma unroll
  for (int h = 1; h < 5; h++) m = fmaxf(m, sc[h]);
  float al[5], den = 0.f;
  #pragma unroll
  for (int h = 0; h < 5; h++){ al[h] = __expf(sc[h] - m); den += al[h]; }
  float inv = 1.f / den;
  float o0 = al[0] * bf2f(zbf[(size_t)an * NC + lane]);
  float o1 = al[0] * bf2f(zbf[(size_t)an * NC + 64 + lane]);
  #pragma unroll
  for (int h = 1; h < 5; h++){
    o0 += al[h] * bf2f(embs[((size_t)(h - 1) * NA + n) * NC + lane]);
    o1 += al[h] * bf2f(embs[((size_t)(h - 1) * NA + n) * NC + 64 + lane]);
  }
  o0 *= inv; o1 *= inv;
  float mx = fmaxf(o0, o1);
  #pragma unroll
  for (int o = 32; o; o >>= 1) mx = fmaxf(mx, __shfl_xor(mx, o));
  float se = __expf(o0 - mx) + __expf(o1 - mx);
  #pragma unroll
  for (int o = 32; o; o >>= 1) se += __shfl_xor(se, o);
  float ls = __logf(se);
  out[(size_t)n * NC + lane]      = o0 - mx - ls;
  out[(size_t)n * NC + 64 + lane] = o1 - mx - ls;
}

// ---------------- launch ----------------

extern "C" void kernel_launch(void* const* d_in, const int* in_sizes, int n_in,
                              void* d_out, int out_size, void* d_ws, size_t ws_size,
                              hipStream_t stream)
{
  const float* x    = (const float*)d_in[0];
  const float* W1   = (const float*)d_in[1];
  const float* W2   = (const float*)d_in[2];
  const float* b2   = (const float*)d_in[3];
  const float* Wg   = (const float*)d_in[4];
  const float* Wa   = (const float*)d_in[5];
  const float* ba   = (const float*)d_in[6];
  const float* va   = (const float*)d_in[7];
  const float* adjv = (const float*)d_in[8];
  const int*   adji = (const int*)d_in[9];
  const int*   idx  = (const int*)d_in[10];
  float* out = (float*)d_out;
  (void)in_sizes; (void)n_in; (void)out_size; (void)ws_size;

  char* w = (char*)d_ws;
  auto alloc = [&](size_t b) -> char* { char* p = w; w += (b + 255) & ~(size_t)255; return p; };
  unsigned short* Scr1 = (unsigned short*)alloc((size_t)NA * NFEAT * 2);  // 51.2MB: binned -> embs
  unsigned short* Hbuf = (unsigned short*)alloc((size_t)NA * HID * 2);    // 51.2MB: GEMM1 out -> aggbf
  unsigned short* W1T  = (unsigned short*)alloc((size_t)HID * NFEAT * 2);
  unsigned short* W2T  = (unsigned short*)alloc((size_t)NC * HID * 2);
  unsigned short* WgT  = (unsigned short*)alloc((size_t)NC * NC * 2);
  unsigned short* WaT  = (unsigned short*)alloc((size_t)NC * NC * 2);
  unsigned short* WfuseT = (unsigned short*)alloc((size_t)AH * NC * 2);
  unsigned short* zbf  = (unsigned short*)alloc((size_t)NA * NC * 2);
  unsigned short* ZWb  = (unsigned short*)alloc((size_t)NA * NC * 2);
  int* fill  = (int*)alloc((size_t)NHOP * NBUCK * 4);
  int* bbase = (int*)alloc((size_t)NHOP * NBUCK * 4);
  int* offs  = (int*)alloc(((size_t)NHOP * NA + 1) * 4);
  long long* pvc = (long long*)alloc((size_t)NHOP * NE * 8);              // CSR records {val, col<<6}
  long long* binned     = (long long*)Scr1;      // live binA..binB
  unsigned short* embs  = Scr1;                  // [4][NA][NC] bf16 (after binB)
  unsigned short* aggbf = Hbuf;                  // [4][NA][NC] bf16 (after GEMM2)
  unsigned short* EW    = (unsigned short*)pvc;  // [4][NA][64] bf16 (pvc dead after gather)

  // merged weight prep (also zeroes fill)
  prep_kernel<<<dim3(1444), 256, 0, stream>>>(W1, W2, Wg, Wa, W1T, W2T, WgT, WaT, WfuseT, fill);

  // z = relu(x@W1)@W2 + b2   (GEMM1 reads x f32 directly: reg-staged cvt, no cast pass)
  gemm_bt<0, 1, 1><<<dim3(1568, 1, 1), 256, 0, stream>>>(x, W1T, Hbuf, nullptr, NA, HID, NFEAT);
  gemm_bt<1, 0, 0><<<dim3(391, 1, 1), 256, 0, stream>>>(Hbuf, W2T, zbf, b2, NA, NC, HID);

  // CSR build: bin -> scan -> fine sort
  binA_kernel<<<dim3((NE + 2047) / 2048, NHOP), 256, 0, stream>>>(adji, adjv, fill, binned);
  bscan_kernel<<<dim3(1), 1024, 0, stream>>>(fill, bbase, offs);
  binB_kernel<<<dim3(NBUCK, NHOP), 256, 0, stream>>>(fill, bbase, binned, offs, pvc);

  // aggregate (converged), then one merged 9-slice GEMM launch
  gather_kernel<<<dim3(NA / GR, NHOP), 256, 0, stream>>>(offs, pvc, zbf, aggbf);
  gemm_sweep<<<dim3(391, 1, 9), 256, 0, stream>>>(aggbf, zbf, WgT, WfuseT, WaT, embs, EW, ZWb);

  // fused softmax-attention + log_softmax
  final_kernel<<<dim3(NA / 4), 256, 0, stream>>>(zbf, embs, ZWb, EW, ba, va, idx, out);
}